// Round 12
// baseline (522.316 us; speedup 1.0000x reference)
//
#include <hip/hip_runtime.h>
#include <cmath>
#include <cstdint>
#include <cstddef>

#define NB 8
#define NPTS 1024
#define BN (NB*NPTS)
#define KNN 20
#define XC_C 512
#define BN_SC 0.99999500003749973f  // 1/sqrt(1+1e-5)

static __device__ __forceinline__ float lrelu(float z) { return z >= 0.f ? z : 0.01f * z; }

// Interleaved DPP max step for TWO independent (lo,hi) u64 chains — R2/R12-validated on HW.
// (Used only by the rare fallback path.)
template<int CTRL>
static __device__ __forceinline__ void dpp_max2(unsigned& loA, unsigned& hiA,
                                                unsigned& loB, unsigned& hiB) {
    unsigned tlA = (unsigned)__builtin_amdgcn_update_dpp(0, (int)loA, CTRL, 0xF, 0xF, false);
    unsigned thA = (unsigned)__builtin_amdgcn_update_dpp(0, (int)hiA, CTRL, 0xF, 0xF, false);
    unsigned tlB = (unsigned)__builtin_amdgcn_update_dpp(0, (int)loB, CTRL, 0xF, 0xF, false);
    unsigned thB = (unsigned)__builtin_amdgcn_update_dpp(0, (int)hiB, CTRL, 0xF, 0xF, false);
    unsigned long long a = ((unsigned long long)hiA << 32) | loA;
    unsigned long long b = ((unsigned long long)thA << 32) | tlA;
    if (b > a) { loA = tlA; hiA = thA; }
    unsigned long long c = ((unsigned long long)hiB << 32) | loB;
    unsigned long long d = ((unsigned long long)thB << 32) | tlB;
    if (d > c) { loB = tlB; hiB = thB; }
}

static __device__ __forceinline__ void wave_max_u64_x2(unsigned long long vA, unsigned long long vB,
                                                       unsigned long long& winA, unsigned long long& winB) {
    unsigned loA = (unsigned)vA, hiA = (unsigned)(vA >> 32);
    unsigned loB = (unsigned)vB, hiB = (unsigned)(vB >> 32);
    dpp_max2<0x121>(loA, hiA, loB, hiB);
    dpp_max2<0x122>(loA, hiA, loB, hiB);
    dpp_max2<0x124>(loA, hiA, loB, hiB);
    dpp_max2<0x128>(loA, hiA, loB, hiB);
    dpp_max2<0x142>(loA, hiA, loB, hiB);   // row_bcast15
    dpp_max2<0x143>(loA, hiA, loB, hiB);   // row_bcast31; lane63 = wave max
    unsigned wloA = (unsigned)__builtin_amdgcn_readlane((int)loA, 63);
    unsigned whiA = (unsigned)__builtin_amdgcn_readlane((int)hiA, 63);
    unsigned wloB = (unsigned)__builtin_amdgcn_readlane((int)loB, 63);
    unsigned whiB = (unsigned)__builtin_amdgcn_readlane((int)hiB, 63);
    winA = ((unsigned long long)whiA << 32) | wloA;
    winB = ((unsigned long long)whiB << 32) | wloB;
}

// ---- cross-lane helpers for the threshold-prune selection path (R1-validated) ----
static __device__ __forceinline__ unsigned long long shflx64(unsigned long long v, int m) {
    int lo = __shfl_xor((int)(unsigned)v, m);
    int hi = __shfl_xor((int)(unsigned)(v >> 32), m);
    return ((unsigned long long)(unsigned)hi << 32) | (unsigned)lo;
}

static __device__ __forceinline__ unsigned long long rdlane64(unsigned long long v, int l) {
    unsigned lo = (unsigned)__builtin_amdgcn_readlane((int)(unsigned)v, l);
    unsigned hi = (unsigned)__builtin_amdgcn_readlane((int)(unsigned)(v >> 32), l);
    return ((unsigned long long)hi << 32) | lo;
}

// 64-lane bitonic sort, descending, TWO independent u64 chains interleaved for ILP.
static __device__ __forceinline__ void bitonic64_desc_x2(unsigned long long& vA,
                                                         unsigned long long& vB, int lane) {
#pragma unroll
    for (int k = 2; k <= 64; k <<= 1) {
#pragma unroll
        for (int j = k >> 1; j > 0; j >>= 1) {
            unsigned long long pA = shflx64(vA, j);
            unsigned long long pB = shflx64(vB, j);
            bool takeMax = (((lane & k) == 0) == ((lane & j) == 0));
            vA = ((pA > vA) == takeMax) ? pA : vA;
            vB = ((pB > vB) == takeMax) ? pB : vB;
        }
    }
}

// ---- R1/R5-validated selection for a pair of rows, from their distance accumulators. ----
static __device__ __forceinline__ void select_pair(const float4* accA, const float4* accB,
                                                   const float4* nm4, int lane,
                                                   unsigned long long (*cw)[64],
                                                   int rA, int rB, int* __restrict__ idx) {
    unsigned long long keyA[16], keyB[16];
#pragma unroll
    for (int j = 0; j < 4; j++) {
        float4 nm = nm4[lane + 64*j];
#pragma unroll
        for (int q = 0; q < 4; q++) {
            int m = 4*(lane + 64*j) + q;
            float fA = 2.f * (&accA[j].x)[q] - (&nm.x)[q];
            unsigned uA = __float_as_uint(fA);
            unsigned sA_ = (unsigned)((int)uA >> 31);
            uA ^= (sA_ | 0x80000000u);
            keyA[4*j+q] = ((unsigned long long)uA << 32) | (unsigned)(1023 - m);
            float fB = 2.f * (&accB[j].x)[q] - (&nm.x)[q];
            unsigned uB = __float_as_uint(fB);
            unsigned sB_ = (unsigned)((int)uB >> 31);
            uB ^= (sB_ | 0x80000000u);
            keyB[4*j+q] = ((unsigned long long)uB << 32) | (unsigned)(1023 - m);
        }
    }

    // per-lane heads
    unsigned long long hA = keyA[0], hB = keyB[0];
#pragma unroll
    for (int i = 1; i < 16; i++) {
        hA = keyA[i] > hA ? keyA[i] : hA;
        hB = keyB[i] > hB ? keyB[i] : hB;
    }

    // L = 20th largest head
    unsigned long long shA = hA, shB = hB;
    bitonic64_desc_x2(shA, shB, lane);
    unsigned long long LA = rdlane64(shA, KNN - 1);
    unsigned long long LB = rdlane64(shB, KNN - 1);

    // count + wave prefix scan
    int cA = 0, cB = 0;
#pragma unroll
    for (int i = 0; i < 16; i++) {
        cA += (keyA[i] >= LA) ? 1 : 0;
        cB += (keyB[i] >= LB) ? 1 : 0;
    }
    int sA = cA, sB = cB;
#pragma unroll
    for (int off = 1; off < 64; off <<= 1) {
        int tA = __shfl_up(sA, off);
        int tB = __shfl_up(sB, off);
        if (lane >= off) { sA += tA; sB += tB; }
    }
    int totA = __builtin_amdgcn_readlane(sA, 63);     // wave-uniform
    int totB = __builtin_amdgcn_readlane(sB, 63);
    int pA = sA - cA, pB = sB - cB;                   // exclusive prefix

    if (totA <= 64 && totB <= 64) {
        int wa = pA, wb = pB;
#pragma unroll
        for (int i = 0; i < 16; i++) {
            if (keyA[i] >= LA) cw[0][wa++] = keyA[i];
            if (keyB[i] >= LB) cw[1][wb++] = keyB[i];
        }
        // same-wave LDS RAW: drain lgkm before reads, block compile-time motion.
        asm volatile("s_waitcnt lgkmcnt(0)" ::: "memory");
        unsigned long long vA = 0ull, vB = 0ull;
        if (lane < totA) vA = cw[0][lane];
        if (lane < totB) vB = cw[1][lane];
        bitonic64_desc_x2(vA, vB, lane);              // sentinels to back; tot >= 20 always
        if (lane < KNN) {
            idx[rA * KNN + lane] = 1023 - (int)(unsigned)vA;
            idx[rB * KNN + lane] = 1023 - (int)(unsigned)vB;
        }
    } else {
        // fallback: per-lane bitonic sort + 20-round DPP pop (wave-uniform branch).
#pragma unroll
        for (int ksz = 2; ksz <= 16; ksz <<= 1) {
#pragma unroll
            for (int jst = ksz >> 1; jst > 0; jst >>= 1) {
#pragma unroll
                for (int i = 0; i < 16; i++) {
                    int l = i ^ jst;
                    if (l > i) {
                        bool dsc = (i & ksz) == 0;
                        unsigned long long a = keyA[i], bbv = keyA[l];
                        bool swA = dsc ? (a < bbv) : (a > bbv);
                        if (swA) { keyA[i] = bbv; keyA[l] = a; }
                        unsigned long long c = keyB[i], d = keyB[l];
                        bool swB = dsc ? (c < d) : (c > d);
                        if (swB) { keyB[i] = d; keyB[l] = c; }
                    }
                }
            }
        }
        int mineA = 0, mineB = 0;
        for (int kk = 0; kk < KNN; kk++) {       // not unrolled
            unsigned long long winA, winB;
            wave_max_u64_x2(keyA[0], keyB[0], winA, winB);
            if (lane == kk) {
                mineA = 1023 - (int)(unsigned)winA;
                mineB = 1023 - (int)(unsigned)winB;
            }
            bool popA = (keyA[0] == winA);
            bool popB = (keyB[0] == winB);
#pragma unroll
            for (int t = 0; t < 15; t++) {
                keyA[t] = popA ? keyA[t+1] : keyA[t];
                keyB[t] = popB ? keyB[t+1] : keyB[t];
            }
            keyA[15] = popA ? 0ull : keyA[15];
            keyB[15] = popB ? 0ull : keyB[15];
        }
        if (lane < KNN) {
            idx[rA * KNN + lane] = mineA;
            idx[rB * KNN + lane] = mineB;
        }
    }
}

// ---- bf16 split helpers (RNE) ----
static __device__ __forceinline__ unsigned short f2bf(float f) {
    unsigned u = __float_as_uint(f);
    unsigned r = u + 0x7fffu + ((u >> 16) & 1u);
    return (unsigned short)(r >> 16);
}
static __device__ __forceinline__ float bf2f(unsigned short h) {
    return __uint_as_float(((unsigned)h) << 16);
}

typedef __attribute__((ext_vector_type(8))) short short8;
typedef __attribute__((ext_vector_type(4))) float floatx4;

// ---- prep: x (B,N,3) -> ft (B,3,N) + norms ----
__global__ void prep_k(const float* __restrict__ x, float* __restrict__ ft, float* __restrict__ nrm) {
    int i = blockIdx.x * 256 + threadIdx.x;   // b*N+n
    if (i >= BN) return;
    int b = i >> 10, n = i & 1023;
    float a = x[3*i], c = x[3*i+1], d = x[3*i+2];
    float* fb = ft + (size_t)b * 3 * NPTS;
    fb[n] = a; fb[NPTS + n] = c; fb[2*NPTS + n] = d;
    nrm[i] = a*a + c*c + d*d;
}

// ---- fused knn, R=4 rows/wave, XCD swizzle, LDS-staged m-stream, WRITE-EARLY pipeline.
// R11 POST-MORTEM: VALUBusy 30% -> barrier stalls on staging loads. Old order per
// chunk: issue load(i+1) -> compute(i) -> write(i+1) -> barrier; the barrier waits on
// write which waits on the load -> window = 1 chunk compute (~1024cy) vs ~900cy HBM
// latency -> residual stall every chunk. NEW order: write(i+1) FIRST (its load was
// issued a full iteration ago) -> issue load(i+2) -> compute(i) -> barrier. The load
// now has compute+barrier+next-iter-write to land. Buffer safety: write to
// buf[(i+1)&1] at iter i start is safe because that buffer's previous readers
// (chunk i-1) finished at iter i-1's barrier. Chain order unchanged -> same idx.
template<int C, int R>
__global__ __launch_bounds__(256, 2) void knn_k(const float* __restrict__ ft,
                                                const float* __restrict__ frow, int frs,
                                                const float* __restrict__ nrm,
                                                int* __restrict__ idx) {
    __shared__ unsigned long long cand[4][2][64];   // 4 KB: per-wave, per-row candidate slots
    __shared__ float sbuf[2 * 4 * NPTS];            // 32 KB: double-buffered 4-channel chunk
    int tid = threadIdx.x;
    int w = tid >> 6;
    int lane = tid & 63;
    int b    = blockIdx.x & 7;              // batch == XCD (round-robin dispatch heuristic)
    int slot = blockIdx.x >> 3;             // row-block within batch
    int r0 = b * NPTS + slot * (4*R) + R * w;   // R consecutive rows per wave
    const float* ftb = ft + (size_t)b * C * NPTS;

    float4 acc[R][4];
#pragma unroll
    for (int rr = 0; rr < R; rr++)
#pragma unroll
        for (int j = 0; j < 4; j++) acc[rr][j] = make_float4(0.f,0.f,0.f,0.f);

    if constexpr ((C & 3) == 0) {
        constexpr int NC = C / 4;
        const float4* cr0 = (const float4*)(frow + (size_t)r0 * frs);
        int frs4 = frs >> 2;
        const float4* src4 = (const float4*)ftb;     // channel c = 256 float4 row
        float* sbase = &sbuf[0];
        float4 pf[4];
        // prologue: chunk 0 -> buf0; issue chunk 1 load
#pragma unroll
        for (int i = 0; i < 4; i++) pf[i] = src4[i*256 + tid];
        {
            float4* sw = (float4*)sbase;
#pragma unroll
            for (int i = 0; i < 4; i++) sw[i*256 + tid] = pf[i];
        }
        if (NC > 1) {
#pragma unroll
            for (int i = 0; i < 4; i++) pf[i] = src4[(size_t)(4+i)*256 + tid];
        }
        __syncthreads();
        for (int c4 = 0; c4 < NC; c4++) {
            // step 1: write chunk c4+1 (loaded one full iteration ago) to its buffer
            if (c4 + 1 < NC) {
                float4* sw = (float4*)(sbase + ((c4+1) & 1) * 4 * NPTS);
#pragma unroll
                for (int i = 0; i < 4; i++) sw[i*256 + tid] = pf[i];
            }
            // step 2: issue load for chunk c4+2 (consumed at iter c4+1's step 1)
            if (c4 + 2 < NC) {
#pragma unroll
                for (int i = 0; i < 4; i++) pf[i] = src4[(size_t)(4*(c4+2)+i)*256 + tid];
            }
            // step 3: compute chunk c4 from buf[c4&1]
            float4 ct[R];
#pragma unroll
            for (int rr = 0; rr < R; rr++) ct[rr] = cr0[c4 + rr*frs4];
            const float4* sc = (const float4*)(sbase + (c4 & 1) * 4 * NPTS);
#pragma unroll
            for (int cc = 0; cc < 4; cc++) {
                const float4* rm = sc + cc*256;
#pragma unroll
                for (int j = 0; j < 4; j++) {
                    float4 v = rm[lane + 64*j];          // LDS, lane-consecutive: conflict-free
#pragma unroll
                    for (int rr = 0; rr < R; rr++) {
                        float cs = (&ct[rr].x)[cc];
                        acc[rr][j].x = fmaf(cs, v.x, acc[rr][j].x);
                        acc[rr][j].y = fmaf(cs, v.y, acc[rr][j].y);
                        acc[rr][j].z = fmaf(cs, v.z, acc[rr][j].z);
                        acc[rr][j].w = fmaf(cs, v.w, acc[rr][j].w);
                    }
                }
            }
            // step 4: make chunk c4+1's writes visible before next iteration reads
            if (c4 + 1 < NC) __syncthreads();
        }
    } else {
        for (int c = 0; c < C; c++) {
            float ct[R];
#pragma unroll
            for (int rr = 0; rr < R; rr++) ct[rr] = frow[(size_t)(r0+rr) * frs + c];
            const float4* rm = (const float4*)(ftb + (size_t)c * NPTS);
#pragma unroll
            for (int j = 0; j < 4; j++) {
                float4 v = rm[lane + 64*j];
#pragma unroll
                for (int rr = 0; rr < R; rr++) {
                    float cs = ct[rr];
                    acc[rr][j].x = fmaf(cs, v.x, acc[rr][j].x);
                    acc[rr][j].y = fmaf(cs, v.y, acc[rr][j].y);
                    acc[rr][j].z = fmaf(cs, v.z, acc[rr][j].z);
                    acc[rr][j].w = fmaf(cs, v.w, acc[rr][j].w);
                }
            }
        }
    }

    const float4* nm4 = (const float4*)(nrm + b * NPTS);
#pragma unroll
    for (int p = 0; p < R/2; p++)
        select_pair(acc[2*p], acc[2*p+1], nm4, lane, cand[w], r0 + 2*p, r0 + 2*p + 1, idx);
}

// ---- H/Ct GEMM: Ht[n,o]=F.w1; Ct[n,o]=F.w2 - Ht + bias ----
template<int C, int O, bool HASB, int RPB>
__global__ void hc_k(const float* __restrict__ F, int FS,
                     const float* __restrict__ w, const float* __restrict__ bias,
                     float* __restrict__ Ht, float* __restrict__ Ct) {
    int r0 = blockIdx.x * RPB;
    int o = threadIdx.x;
    const float* wr = w + (size_t)o * (2*C);
    float h[RPB], a2[RPB];
#pragma unroll
    for (int nn = 0; nn < RPB; nn++) { h[nn] = 0.f; a2[nn] = 0.f; }
    if constexpr ((C & 3) == 0) {
        const float4* w1 = (const float4*)wr;
        const float4* w2 = (const float4*)(wr + C);
#pragma unroll 4
        for (int c4 = 0; c4 < C/4; c4++) {
            float4 wa = w1[c4], wb = w2[c4];
#pragma unroll
            for (int nn = 0; nn < RPB; nn++) {
                float4 f = *(const float4*)(F + (size_t)(r0+nn)*FS + 4*c4);  // broadcast
                h[nn]  = fmaf(wa.x,f.x, fmaf(wa.y,f.y, fmaf(wa.z,f.z, fmaf(wa.w,f.w, h[nn]))));
                a2[nn] = fmaf(wb.x,f.x, fmaf(wb.y,f.y, fmaf(wb.z,f.z, fmaf(wb.w,f.w, a2[nn]))));
            }
        }
    } else {
        for (int c = 0; c < C; c++) {
            float wa = wr[c], wb = wr[C+c];
#pragma unroll
            for (int nn = 0; nn < RPB; nn++) {
                float f = F[(size_t)(r0+nn)*FS + c];
                h[nn]  = fmaf(wa, f, h[nn]);
                a2[nn] = fmaf(wb, f, a2[nn]);
            }
        }
    }
    float bs = 0.f;
    if constexpr (HASB) bs = bias[o];
#pragma unroll
    for (int nn = 0; nn < RPB; nn++) {
        size_t ro = (size_t)(r0+nn)*O + o;
        Ht[ro] = h[nn];
        Ct[ro] = a2[nn] - h[nn] + bs;
    }
}

// ---- gather + max_k + bn + lrelu; optional transposed-feature + norms for next knn ----
// XCD-swizzled r mapping (R8-validated): batch = blockIdx&7 keeps gathers in-XCD.
template<int O, bool WFT>
__global__ void gmax_k(const float* __restrict__ Ht, const float* __restrict__ Ct,
                       const int* __restrict__ idx,
                       const float* __restrict__ g, const float* __restrict__ bb,
                       float* __restrict__ xcs, float* __restrict__ ft, float* __restrict__ nrm) {
    int b = blockIdx.x & 7;
    int n = blockIdx.x >> 3;
    int r = b * NPTS + n;
    int o = threadIdx.x;
    const int* id = idx + r * KNN;
    float vmax = -INFINITY, vmin = INFINITY;
    const float* hb = Ht + (size_t)b * NPTS * O + o;
#pragma unroll 4
    for (int k = 0; k < KNN; k++) {
        int m = id[k];                 // broadcast
        float v = hb[(size_t)m * O];   // coalesced across o
        vmax = fmaxf(vmax, v); vmin = fminf(vmin, v);
    }
    float ct = Ct[(size_t)r * O + o];
    float s = g[o] * BN_SC;
    float pre = (s >= 0.f ? vmax : vmin) + ct;
    float out = lrelu(fmaf(s, pre, bb[o]));
    xcs[(size_t)r * XC_C + o] = out;
    if constexpr (WFT) {
        ft[((size_t)b * O + o) * NPTS + n] = out;
        float sq = out * out;
#pragma unroll
        for (int off = 32; off > 0; off >>= 1) sq += __shfl_xor(sq, off);
        __shared__ float red[O/64 > 0 ? O/64 : 1];
        if ((o & 63) == 0) red[o >> 6] = sq;
        __syncthreads();
        if (o == 0) {
            float t = 0.f;
#pragma unroll
            for (int i = 0; i < O/64; i++) t += red[i];
            nrm[r] = t;
        }
    }
}

// ---- split-bf16 conversions for conv5 MFMA ----
__global__ void xcvt_k(const float* __restrict__ xc,
                       unsigned short* __restrict__ xh, unsigned short* __restrict__ xl) {
    int i = blockIdx.x * 256 + threadIdx.x;   // BN*512
    float v = xc[i];
    unsigned short h = f2bf(v);
    xh[i] = h;
    xl[i] = f2bf(v - bf2f(h));
}

__global__ void wcvt_k(const float* __restrict__ w5,
                       unsigned short* __restrict__ wh, unsigned short* __restrict__ wl) {
    int i = blockIdx.x * 256 + threadIdx.x;   // 1024*512, (o,c) row-major kept
    float v = w5[i];
    unsigned short h = f2bf(v);
    wh[i] = h;
    wl[i] = f2bf(v - bf2f(h));
}

// ---- conv5 A/B (within-run, container-noise-free): 32-row vs 64-row n-tile.
// Both variants have the T14 hoist; per-output accumulation chain identical ->
// bit-identical outputs regardless of split. b = blockIdx.z + bofs.
__global__ __launch_bounds__(256) void conv5mfma32_k(const unsigned short* __restrict__ xh,
                                                     const unsigned short* __restrict__ xl,
                                                     const unsigned short* __restrict__ wh,
                                                     const unsigned short* __restrict__ wl,
                                                     float* __restrict__ part, int bofs) {
    __shared__ short ah_s[32*72];
    __shared__ short al_s[32*72];
    __shared__ short bh_s[128*72];
    __shared__ short bl_s[128*72];
    int b = blockIdx.z + bofs, og = blockIdx.y, nt = blockIdx.x;   // nt 0..31
    int tid = threadIdx.x;
    int w = tid >> 6, lane = tid & 63;
    int m = lane & 15, quad = lane >> 4;
    int h = w >> 1, q = w & 1;
    size_t nbase = (size_t)b * NPTS + nt * 32;
    int obase = og * 128;
    int srow = tid >> 3;
    int scol = (tid & 7) * 8;

    floatx4 acc[4];
#pragma unroll
    for (int t = 0; t < 4; t++) acc[t] = (floatx4){0.f, 0.f, 0.f, 0.f};

    for (int kc = 0; kc < 512; kc += 64) {
        short8 pa[2], pb[8];
        pa[0] = *(const short8*)(xh + (nbase + srow)*512 + kc + scol);
        pa[1] = *(const short8*)(xl + (nbase + srow)*512 + kc + scol);
#pragma unroll
        for (int i = 0; i < 4; i++) {
            int r = srow + i*32;
            pb[2*i]   = *(const short8*)(wh + (size_t)(obase + r)*512 + kc + scol);
            pb[2*i+1] = *(const short8*)(wl + (size_t)(obase + r)*512 + kc + scol);
        }
        __syncthreads();
        *(short8*)(ah_s + srow*72 + scol) = pa[0];
        *(short8*)(al_s + srow*72 + scol) = pa[1];
#pragma unroll
        for (int i = 0; i < 4; i++) {
            int r = srow + i*32;
            *(short8*)(bh_s + r*72 + scol) = pb[2*i];
            *(short8*)(bl_s + r*72 + scol) = pb[2*i+1];
        }
        __syncthreads();
#pragma unroll
        for (int kk = 0; kk < 2; kk++) {
            short8 ah8 = *(const short8*)(ah_s + (h*16 + m)*72 + kk*32 + quad*8);
            short8 al8 = *(const short8*)(al_s + (h*16 + m)*72 + kk*32 + quad*8);
#pragma unroll
            for (int t = 0; t < 4; t++) {
                short8 bh8 = *(const short8*)(bh_s + (q*64 + t*16 + m)*72 + kk*32 + quad*8);
                short8 bl8 = *(const short8*)(bl_s + (q*64 + t*16 + m)*72 + kk*32 + quad*8);
                acc[t] = __builtin_amdgcn_mfma_f32_16x16x32_bf16(ah8, bh8, acc[t], 0, 0, 0);
                acc[t] = __builtin_amdgcn_mfma_f32_16x16x32_bf16(ah8, bl8, acc[t], 0, 0, 0);
                acc[t] = __builtin_amdgcn_mfma_f32_16x16x32_bf16(al8, bh8, acc[t], 0, 0, 0);
            }
        }
    }
#pragma unroll
    for (int t = 0; t < 4; t++) {
        float v = fmaxf(fmaxf(acc[t][0], acc[t][1]), fmaxf(acc[t][2], acc[t][3]));
        v = fmaxf(v, __shfl_xor(v, 16));
        v = fmaxf(v, __shfl_xor(v, 32));
        if (quad == 0)
            part[((size_t)b * 64 + nt*2 + h) * 1024 + obase + q*64 + t*16 + m] = v;
    }
}

__global__ __launch_bounds__(256) void conv5mfma64_k(const unsigned short* __restrict__ xh,
                                                     const unsigned short* __restrict__ xl,
                                                     const unsigned short* __restrict__ wh,
                                                     const unsigned short* __restrict__ wl,
                                                     float* __restrict__ part, int bofs) {
    __shared__ short ah_s[64*72];
    __shared__ short al_s[64*72];
    __shared__ short bh_s[128*72];
    __shared__ short bl_s[128*72];
    int b = blockIdx.z + bofs, og = blockIdx.y, nt = blockIdx.x;   // nt 0..15
    int tid = threadIdx.x;
    int w = tid >> 6, lane = tid & 63;
    int m = lane & 15, quad = lane >> 4;
    int h = w >> 1, q = w & 1;
    size_t nbase = (size_t)b * NPTS + nt * 64;
    int obase = og * 128;
    int srow = tid >> 3;
    int scol = (tid & 7) * 8;

    floatx4 acc[2][4];
#pragma unroll
    for (int i = 0; i < 2; i++)
#pragma unroll
        for (int t = 0; t < 4; t++) acc[i][t] = (floatx4){0.f, 0.f, 0.f, 0.f};

    for (int kc = 0; kc < 512; kc += 64) {
        short8 pa[4], pb[8];
        pa[0] = *(const short8*)(xh + (nbase + srow)*512 + kc + scol);
        pa[1] = *(const short8*)(xl + (nbase + srow)*512 + kc + scol);
        pa[2] = *(const short8*)(xh + (nbase + 32 + srow)*512 + kc + scol);
        pa[3] = *(const short8*)(xl + (nbase + 32 + srow)*512 + kc + scol);
#pragma unroll
        for (int i = 0; i < 4; i++) {
            int r = srow + i*32;
            pb[2*i]   = *(const short8*)(wh + (size_t)(obase + r)*512 + kc + scol);
            pb[2*i+1] = *(const short8*)(wl + (size_t)(obase + r)*512 + kc + scol);
        }
        __syncthreads();
        *(short8*)(ah_s + srow*72 + scol)      = pa[0];
        *(short8*)(al_s + srow*72 + scol)      = pa[1];
        *(short8*)(ah_s + (32+srow)*72 + scol) = pa[2];
        *(short8*)(al_s + (32+srow)*72 + scol) = pa[3];
#pragma unroll
        for (int i = 0; i < 4; i++) {
            int r = srow + i*32;
            *(short8*)(bh_s + r*72 + scol) = pb[2*i];
            *(short8*)(bl_s + r*72 + scol) = pb[2*i+1];
        }
        __syncthreads();
#pragma unroll
        for (int kk = 0; kk < 2; kk++) {
            short8 ah8[2], al8[2];
#pragma unroll
            for (int i = 0; i < 2; i++) {
                ah8[i] = *(const short8*)(ah_s + (i*32 + h*16 + m)*72 + kk*32 + quad*8);
                al8[i] = *(const short8*)(al_s + (i*32 + h*16 + m)*72 + kk*32 + quad*8);
            }
#pragma unroll
            for (int t = 0; t < 4; t++) {
                short8 bh8 = *(const short8*)(bh_s + (q*64 + t*16 + m)*72 + kk*32 + quad*8);
                short8 bl8 = *(const short8*)(bl_s + (q*64 + t*16 + m)*72 + kk*32 + quad*8);
#pragma unroll
                for (int i = 0; i < 2; i++) {
                    acc[i][t] = __builtin_amdgcn_mfma_f32_16x16x32_bf16(ah8[i], bh8, acc[i][t], 0, 0, 0);
                    acc[i][t] = __builtin_amdgcn_mfma_f32_16x16x32_bf16(ah8[i], bl8, acc[i][t], 0, 0, 0);
                    acc[i][t] = __builtin_amdgcn_mfma_f32_16x16x32_bf16(al8[i], bh8, acc[i][t], 0, 0, 0);
                }
            }
        }
    }
#pragma unroll
    for (int i = 0; i < 2; i++)
#pragma unroll
    for (int t = 0; t < 4; t++) {
        float v = fmaxf(fmaxf(acc[i][t][0], acc[i][t][1]), fmaxf(acc[i][t][2], acc[i][t][3]));
        v = fmaxf(v, __shfl_xor(v, 16));
        v = fmaxf(v, __shfl_xor(v, 32));
        if (quad == 0)
            part[((size_t)b * 64 + nt*4 + i*2 + h) * 1024 + obase + q*64 + t*16 + m] = v;
    }
}

// ---- global max pool: gp[b,o] = max_j part[b,j,o] ----
__global__ void gpool_k(const float* __restrict__ part, float* __restrict__ gp) {
    int i = blockIdx.x * 256 + threadIdx.x;   // b*1024+o
    int b = i >> 10, o = i & 1023;
    const float* pb = part + (size_t)b * 64 * 1024 + o;
    float m = pb[0];
#pragma unroll 4
    for (int j = 1; j < 64; j++) m = fmaxf(m, pb[(size_t)j * 1024]);
    gp[i] = m;
}

// ---- linear layer, one wave per output dot ----
template<int C, bool HASBIAS, bool ACT>
__global__ __launch_bounds__(256) void lin_k(const float* __restrict__ X, int xs,
                                             const float* __restrict__ W,
                                             const float* __restrict__ bias,
                                             const float* __restrict__ g, const float* __restrict__ bb,
                                             float* __restrict__ Y, int ys) {
    int wid = (blockIdx.x * 256 + threadIdx.x) >> 6;
    int lane = threadIdx.x & 63;
    int o = wid >> 3;          // NB = 8
    int b = wid & 7;
    const float4* wr = (const float4*)(W + (size_t)o * C);
    const float4* xr = (const float4*)(X + (size_t)b * xs);
    float acc = 0.f;
#pragma unroll
    for (int i = 0; i < C/256; i++) {
        float4 w = wr[lane + 64*i];
        float4 xv = xr[lane + 64*i];
        acc = fmaf(w.x,xv.x, fmaf(w.y,xv.y, fmaf(w.z,xv.z, fmaf(w.w,xv.w, acc))));
    }
#pragma unroll
    for (int off = 32; off > 0; off >>= 1) acc += __shfl_xor(acc, off);
    if (lane == 0) {
        if constexpr (HASBIAS) acc += bias[o];
        if constexpr (ACT) acc = lrelu(fmaf(acc, g[o] * BN_SC, bb[o]));
        Y[(size_t)b * ys + o] = acc;
    }
}

extern "C" void kernel_launch(void* const* d_in, const int* in_sizes, int n_in,
                              void* d_out, int out_size, void* d_ws, size_t ws_size,
                              hipStream_t stream) {
    const float* x       = (const float*)d_in[0];
    const float* conv1_w = (const float*)d_in[1];
    const float* conv1_b = (const float*)d_in[2];
    const float* bn1_g   = (const float*)d_in[3];
    const float* bn1_b   = (const float*)d_in[4];
    const float* conv2_w = (const float*)d_in[5];
    const float* bn2_g   = (const float*)d_in[6];
    const float* bn2_b   = (const float*)d_in[7];
    const float* conv3_w = (const float*)d_in[8];
    const float* bn3_g   = (const float*)d_in[9];
    const float* bn3_b   = (const float*)d_in[10];
    const float* conv4_w = (const float*)d_in[11];
    const float* bn4_g   = (const float*)d_in[12];
    const float* bn4_b   = (const float*)d_in[13];
    const float* conv5_w = (const float*)d_in[14];
    const float* lin1_w  = (const float*)d_in[15];
    const float* bn6_g   = (const float*)d_in[16];
    const float* bn6_b   = (const float*)d_in[17];
    const float* lin2_w  = (const float*)d_in[18];
    const float* lin2_b  = (const float*)d_in[19];
    const float* bn7_g   = (const float*)d_in[20];
    const float* bn7_b   = (const float*)d_in[21];
    const float* lin3_w  = (const float*)d_in[22];
    const float* lin3_b  = (const float*)d_in[23];
    float* outp = (float*)d_out;

    // workspace layout (floats): total 10,657,792 f = 42.6 MB
    float* ws   = (float*)d_ws;
    float* xc   = ws;                          // (BN,512)          4,194,304
    int*   idxb = (int*)(ws + 4194304);        // (BN,20)             163,840
    float* nrm  = ws + 4194304 + 163840;       // (BN)                  8,192
    float* ft   = nrm + 8192;                  // (B,<=128,N)       1,048,576
    float* part = ft + 1048576;                // (B,64,1024)         524,288
    float* w5t  = part + 524288;               // bf16 wh/wl          524,288
    float* Ht   = w5t + 524288;                // (BN,<=256) / xh   2,097,152
    float* Ct   = Ht + 2097152;                // (BN,<=256) / xl   2,097,152
    // head scratch aliases ft (dead after the last knn_k):
    float* gp   = ft;                          // (8,1024)
    float* y1   = ft + 8192;                   // (8,512)
    float* y2   = ft + 8192 + 4096;            // (8,256)
    // split-bf16 aliases (dead regions after stage 4):
    unsigned short* xhp = (unsigned short*)Ht;       // BN*512 shorts
    unsigned short* xlp = (unsigned short*)Ct;
    unsigned short* whp = (unsigned short*)w5t;      // 1024*512 shorts
    unsigned short* wlp = whp + 1024*512;

    prep_k<<<BN/256, 256, 0, stream>>>(x, ft, nrm);

    // Stage 1: C=3 (coords), O=64, with conv bias; R=4 + XCD swizzle
    knn_k<3, 4><<<BN/16, 256, 0, stream>>>(ft, x, 3, nrm, idxb);
    hc_k<3, 64, true, 4><<<BN/4, 64, 0, stream>>>(x, 3, conv1_w, conv1_b, Ht, Ct);
    gmax_k<64, true><<<BN, 64, 0, stream>>>(Ht, Ct, idxb, bn1_g, bn1_b, xc + 0, ft, nrm);

    // Stage 2: C=64 -> O=64; LDS-staged m-stream (write-early pipeline)
    knn_k<64, 4><<<BN/16, 256, 0, stream>>>(ft, xc + 0, XC_C, nrm, idxb);
    hc_k<64, 64, false, 4><<<BN/4, 64, 0, stream>>>(xc + 0, XC_C, conv2_w, nullptr, Ht, Ct);
    gmax_k<64, true><<<BN, 64, 0, stream>>>(Ht, Ct, idxb, bn2_g, bn2_b, xc + 64, ft, nrm);

    // Stage 3: C=64 -> O=128
    knn_k<64, 4><<<BN/16, 256, 0, stream>>>(ft, xc + 64, XC_C, nrm, idxb);
    hc_k<64, 128, false, 4><<<BN/4, 128, 0, stream>>>(xc + 64, XC_C, conv3_w, nullptr, Ht, Ct);
    gmax_k<128, true><<<BN, 128, 0, stream>>>(Ht, Ct, idxb, bn3_g, bn3_b, xc + 128, ft, nrm);

    // Stage 4: C=128 -> O=256 (no next knn)
    knn_k<128, 4><<<BN/16, 256, 0, stream>>>(ft, xc + 128, XC_C, nrm, idxb);
    hc_k<128, 256, false, 8><<<BN/8, 256, 0, stream>>>(xc + 128, XC_C, conv4_w, nullptr, Ht, Ct);
    gmax_k<256, false><<<BN, 256, 0, stream>>>(Ht, Ct, idxb, bn4_g, bn4_b, xc + 256, nullptr, nullptr);

    // conv5: within-run A/B — 32-row tile on batches 0..3, 64-row tile on 4..7.
    xcvt_k<<<BN*512/256, 256, 0, stream>>>(xc, xhp, xlp);
    wcvt_k<<<1024*512/256, 256, 0, stream>>>(conv5_w, whp, wlp);
    conv5mfma32_k<<<dim3(32, 8, 4), 256, 0, stream>>>(xhp, xlp, whp, wlp, part, 0);
    conv5mfma64_k<<<dim3(16, 8, 4), 256, 0, stream>>>(xhp, xlp, whp, wlp, part, 4);
    gpool_k<<<NB*1024/256, 256, 0, stream>>>(part, gp);
    lin_k<1024, false, true><<<NB*512/4, 256, 0, stream>>>(gp, 1024, lin1_w, nullptr, bn6_g, bn6_b, y1, 512);
    lin_k<512,  true,  true><<<NB*256/4, 256, 0, stream>>>(y1, 512, lin2_w, lin2_b, bn7_g, bn7_b, y2, 256);
    lin_k<256,  true, false><<<NB*40/4,  256, 0, stream>>>(y2, 256, lin3_w, lin3_b, nullptr, nullptr, outp, 40);
}

// Round 13
// 463.821 us; speedup vs baseline: 1.1261x; 1.1261x over previous
//
#include <hip/hip_runtime.h>
#include <cmath>
#include <cstdint>
#include <cstddef>

#define NB 8
#define NPTS 1024
#define BN (NB*NPTS)
#define KNN 20
#define XC_C 512
#define BN_SC 0.99999500003749973f  // 1/sqrt(1+1e-5)

static __device__ __forceinline__ float lrelu(float z) { return z >= 0.f ? z : 0.01f * z; }

// Interleaved DPP max step for TWO independent (lo,hi) u64 chains — R2/R12-validated on HW.
// (Used only by the rare fallback path.)
template<int CTRL>
static __device__ __forceinline__ void dpp_max2(unsigned& loA, unsigned& hiA,
                                                unsigned& loB, unsigned& hiB) {
    unsigned tlA = (unsigned)__builtin_amdgcn_update_dpp(0, (int)loA, CTRL, 0xF, 0xF, false);
    unsigned thA = (unsigned)__builtin_amdgcn_update_dpp(0, (int)hiA, CTRL, 0xF, 0xF, false);
    unsigned tlB = (unsigned)__builtin_amdgcn_update_dpp(0, (int)loB, CTRL, 0xF, 0xF, false);
    unsigned thB = (unsigned)__builtin_amdgcn_update_dpp(0, (int)hiB, CTRL, 0xF, 0xF, false);
    unsigned long long a = ((unsigned long long)hiA << 32) | loA;
    unsigned long long b = ((unsigned long long)thA << 32) | tlA;
    if (b > a) { loA = tlA; hiA = thA; }
    unsigned long long c = ((unsigned long long)hiB << 32) | loB;
    unsigned long long d = ((unsigned long long)thB << 32) | tlB;
    if (d > c) { loB = tlB; hiB = thB; }
}

static __device__ __forceinline__ void wave_max_u64_x2(unsigned long long vA, unsigned long long vB,
                                                       unsigned long long& winA, unsigned long long& winB) {
    unsigned loA = (unsigned)vA, hiA = (unsigned)(vA >> 32);
    unsigned loB = (unsigned)vB, hiB = (unsigned)(vB >> 32);
    dpp_max2<0x121>(loA, hiA, loB, hiB);
    dpp_max2<0x122>(loA, hiA, loB, hiB);
    dpp_max2<0x124>(loA, hiA, loB, hiB);
    dpp_max2<0x128>(loA, hiA, loB, hiB);
    dpp_max2<0x142>(loA, hiA, loB, hiB);   // row_bcast15
    dpp_max2<0x143>(loA, hiA, loB, hiB);   // row_bcast31; lane63 = wave max
    unsigned wloA = (unsigned)__builtin_amdgcn_readlane((int)loA, 63);
    unsigned whiA = (unsigned)__builtin_amdgcn_readlane((int)hiA, 63);
    unsigned wloB = (unsigned)__builtin_amdgcn_readlane((int)loB, 63);
    unsigned whiB = (unsigned)__builtin_amdgcn_readlane((int)hiB, 63);
    winA = ((unsigned long long)whiA << 32) | wloA;
    winB = ((unsigned long long)whiB << 32) | wloB;
}

// ---- cross-lane helpers for the threshold-prune selection path (R1-validated) ----
static __device__ __forceinline__ unsigned long long shflx64(unsigned long long v, int m) {
    int lo = __shfl_xor((int)(unsigned)v, m);
    int hi = __shfl_xor((int)(unsigned)(v >> 32), m);
    return ((unsigned long long)(unsigned)hi << 32) | (unsigned)lo;
}

static __device__ __forceinline__ unsigned long long rdlane64(unsigned long long v, int l) {
    unsigned lo = (unsigned)__builtin_amdgcn_readlane((int)(unsigned)v, l);
    unsigned hi = (unsigned)__builtin_amdgcn_readlane((int)(unsigned)(v >> 32), l);
    return ((unsigned long long)hi << 32) | lo;
}

// 64-lane bitonic sort, descending, TWO independent u64 chains interleaved for ILP.
static __device__ __forceinline__ void bitonic64_desc_x2(unsigned long long& vA,
                                                         unsigned long long& vB, int lane) {
#pragma unroll
    for (int k = 2; k <= 64; k <<= 1) {
#pragma unroll
        for (int j = k >> 1; j > 0; j >>= 1) {
            unsigned long long pA = shflx64(vA, j);
            unsigned long long pB = shflx64(vB, j);
            bool takeMax = (((lane & k) == 0) == ((lane & j) == 0));
            vA = ((pA > vA) == takeMax) ? pA : vA;
            vB = ((pB > vB) == takeMax) ? pB : vB;
        }
    }
}

// ---- R1/R5-validated selection for a pair of rows, from their distance accumulators. ----
static __device__ __forceinline__ void select_pair(const float4* accA, const float4* accB,
                                                   const float4* nm4, int lane,
                                                   unsigned long long (*cw)[64],
                                                   int rA, int rB, int* __restrict__ idx) {
    unsigned long long keyA[16], keyB[16];
#pragma unroll
    for (int j = 0; j < 4; j++) {
        float4 nm = nm4[lane + 64*j];
#pragma unroll
        for (int q = 0; q < 4; q++) {
            int m = 4*(lane + 64*j) + q;
            float fA = 2.f * (&accA[j].x)[q] - (&nm.x)[q];
            unsigned uA = __float_as_uint(fA);
            unsigned sA_ = (unsigned)((int)uA >> 31);
            uA ^= (sA_ | 0x80000000u);
            keyA[4*j+q] = ((unsigned long long)uA << 32) | (unsigned)(1023 - m);
            float fB = 2.f * (&accB[j].x)[q] - (&nm.x)[q];
            unsigned uB = __float_as_uint(fB);
            unsigned sB_ = (unsigned)((int)uB >> 31);
            uB ^= (sB_ | 0x80000000u);
            keyB[4*j+q] = ((unsigned long long)uB << 32) | (unsigned)(1023 - m);
        }
    }

    // per-lane heads
    unsigned long long hA = keyA[0], hB = keyB[0];
#pragma unroll
    for (int i = 1; i < 16; i++) {
        hA = keyA[i] > hA ? keyA[i] : hA;
        hB = keyB[i] > hB ? keyB[i] : hB;
    }

    // L = 20th largest head
    unsigned long long shA = hA, shB = hB;
    bitonic64_desc_x2(shA, shB, lane);
    unsigned long long LA = rdlane64(shA, KNN - 1);
    unsigned long long LB = rdlane64(shB, KNN - 1);

    // count + wave prefix scan
    int cA = 0, cB = 0;
#pragma unroll
    for (int i = 0; i < 16; i++) {
        cA += (keyA[i] >= LA) ? 1 : 0;
        cB += (keyB[i] >= LB) ? 1 : 0;
    }
    int sA = cA, sB = cB;
#pragma unroll
    for (int off = 1; off < 64; off <<= 1) {
        int tA = __shfl_up(sA, off);
        int tB = __shfl_up(sB, off);
        if (lane >= off) { sA += tA; sB += tB; }
    }
    int totA = __builtin_amdgcn_readlane(sA, 63);     // wave-uniform
    int totB = __builtin_amdgcn_readlane(sB, 63);
    int pA = sA - cA, pB = sB - cB;                   // exclusive prefix

    if (totA <= 64 && totB <= 64) {
        int wa = pA, wb = pB;
#pragma unroll
        for (int i = 0; i < 16; i++) {
            if (keyA[i] >= LA) cw[0][wa++] = keyA[i];
            if (keyB[i] >= LB) cw[1][wb++] = keyB[i];
        }
        // same-wave LDS RAW: drain lgkm before reads, block compile-time motion.
        asm volatile("s_waitcnt lgkmcnt(0)" ::: "memory");
        unsigned long long vA = 0ull, vB = 0ull;
        if (lane < totA) vA = cw[0][lane];
        if (lane < totB) vB = cw[1][lane];
        bitonic64_desc_x2(vA, vB, lane);              // sentinels to back; tot >= 20 always
        if (lane < KNN) {
            idx[rA * KNN + lane] = 1023 - (int)(unsigned)vA;
            idx[rB * KNN + lane] = 1023 - (int)(unsigned)vB;
        }
    } else {
        // fallback: per-lane bitonic sort + 20-round DPP pop (wave-uniform branch).
#pragma unroll
        for (int ksz = 2; ksz <= 16; ksz <<= 1) {
#pragma unroll
            for (int jst = ksz >> 1; jst > 0; jst >>= 1) {
#pragma unroll
                for (int i = 0; i < 16; i++) {
                    int l = i ^ jst;
                    if (l > i) {
                        bool dsc = (i & ksz) == 0;
                        unsigned long long a = keyA[i], bbv = keyA[l];
                        bool swA = dsc ? (a < bbv) : (a > bbv);
                        if (swA) { keyA[i] = bbv; keyA[l] = a; }
                        unsigned long long c = keyB[i], d = keyB[l];
                        bool swB = dsc ? (c < d) : (c > d);
                        if (swB) { keyB[i] = d; keyB[l] = c; }
                    }
                }
            }
        }
        int mineA = 0, mineB = 0;
        for (int kk = 0; kk < KNN; kk++) {       // not unrolled
            unsigned long long winA, winB;
            wave_max_u64_x2(keyA[0], keyB[0], winA, winB);
            if (lane == kk) {
                mineA = 1023 - (int)(unsigned)winA;
                mineB = 1023 - (int)(unsigned)winB;
            }
            bool popA = (keyA[0] == winA);
            bool popB = (keyB[0] == winB);
#pragma unroll
            for (int t = 0; t < 15; t++) {
                keyA[t] = popA ? keyA[t+1] : keyA[t];
                keyB[t] = popB ? keyB[t+1] : keyB[t];
            }
            keyA[15] = popA ? 0ull : keyA[15];
            keyB[15] = popB ? 0ull : keyB[15];
        }
        if (lane < KNN) {
            idx[rA * KNN + lane] = mineA;
            idx[rB * KNN + lane] = mineB;
        }
    }
}

// ---- bf16 split helpers (RNE) ----
static __device__ __forceinline__ unsigned short f2bf(float f) {
    unsigned u = __float_as_uint(f);
    unsigned r = u + 0x7fffu + ((u >> 16) & 1u);
    return (unsigned short)(r >> 16);
}
static __device__ __forceinline__ float bf2f(unsigned short h) {
    return __uint_as_float(((unsigned)h) << 16);
}

typedef __attribute__((ext_vector_type(8))) short short8;
typedef __attribute__((ext_vector_type(4))) float floatx4;

// ---- prep: x (B,N,3) -> ft (B,3,N) + norms ----
__global__ void prep_k(const float* __restrict__ x, float* __restrict__ ft, float* __restrict__ nrm) {
    int i = blockIdx.x * 256 + threadIdx.x;   // b*N+n
    if (i >= BN) return;
    int b = i >> 10, n = i & 1023;
    float a = x[3*i], c = x[3*i+1], d = x[3*i+2];
    float* fb = ft + (size_t)b * 3 * NPTS;
    fb[n] = a; fb[NPTS + n] = c; fb[2*NPTS + n] = d;
    nrm[i] = a*a + c*c + d*d;
}

// ---- fused knn, R=4 rows/wave, XCD swizzle, LDS-staged m-stream.
// R10-VALIDATED pipeline (knn<128> ~48-58us, FETCH 4.3MB, WRITE 640KB):
// per chunk: issue load(i+1) -> compute(i) -> write(i+1) -> barrier. pf's live range
// stays WITHIN one iteration (no cross-barrier liveness).
// R12 POST-MORTEM: the write-early variant (write(i+1) before compute) forced pf to
// live ACROSS the barrier -> allocator spilled (WRITE 54MB, knn 102us). REVERTED.
// Chain order (cc 0..3, j, rr) byte-identical -> same keys -> same idx -> absmax 0.0.
template<int C, int R>
__global__ __launch_bounds__(256, 2) void knn_k(const float* __restrict__ ft,
                                                const float* __restrict__ frow, int frs,
                                                const float* __restrict__ nrm,
                                                int* __restrict__ idx) {
    __shared__ unsigned long long cand[4][2][64];   // 4 KB: per-wave, per-row candidate slots
    __shared__ float sbuf[2 * 4 * NPTS];            // 32 KB: double-buffered 4-channel chunk
    int tid = threadIdx.x;
    int w = tid >> 6;
    int lane = tid & 63;
    int b    = blockIdx.x & 7;              // batch == XCD (round-robin dispatch heuristic)
    int slot = blockIdx.x >> 3;             // row-block within batch
    int r0 = b * NPTS + slot * (4*R) + R * w;   // R consecutive rows per wave
    const float* ftb = ft + (size_t)b * C * NPTS;

    float4 acc[R][4];
#pragma unroll
    for (int rr = 0; rr < R; rr++)
#pragma unroll
        for (int j = 0; j < 4; j++) acc[rr][j] = make_float4(0.f,0.f,0.f,0.f);

    if constexpr ((C & 3) == 0) {
        constexpr int NC = C / 4;
        const float4* cr0 = (const float4*)(frow + (size_t)r0 * frs);
        int frs4 = frs >> 2;
        const float4* src4 = (const float4*)ftb;     // channel c = 256 float4 row
        float* sbase = &sbuf[0];
        float4 pf[4];
        // prologue: stage chunk 0 (channels 0..3) -> buf0
#pragma unroll
        for (int i = 0; i < 4; i++) pf[i] = src4[i*256 + tid];
        {
            float4* sw = (float4*)sbase;
#pragma unroll
            for (int i = 0; i < 4; i++) sw[i*256 + tid] = pf[i];
        }
        __syncthreads();
        for (int c4 = 0; c4 < NC; c4++) {
            int cur = c4 & 1;
            if (c4 + 1 < NC) {               // issue next chunk's global loads early
#pragma unroll
                for (int i = 0; i < 4; i++) pf[i] = src4[(size_t)(4*(c4+1)+i)*256 + tid];
            }
            float4 ct[R];
#pragma unroll
            for (int rr = 0; rr < R; rr++) ct[rr] = cr0[c4 + rr*frs4];
            const float4* sc = (const float4*)(sbase + cur * 4 * NPTS);
#pragma unroll
            for (int cc = 0; cc < 4; cc++) {
                const float4* rm = sc + cc*256;
#pragma unroll
                for (int j = 0; j < 4; j++) {
                    float4 v = rm[lane + 64*j];          // LDS, lane-consecutive: conflict-free
#pragma unroll
                    for (int rr = 0; rr < R; rr++) {
                        float cs = (&ct[rr].x)[cc];
                        acc[rr][j].x = fmaf(cs, v.x, acc[rr][j].x);
                        acc[rr][j].y = fmaf(cs, v.y, acc[rr][j].y);
                        acc[rr][j].z = fmaf(cs, v.z, acc[rr][j].z);
                        acc[rr][j].w = fmaf(cs, v.w, acc[rr][j].w);
                    }
                }
            }
            if (c4 + 1 < NC) {
                // write next chunk to the other buffer: its readers (chunk c4-1)
                // all passed the previous barrier -> safe without a pre-write sync.
                float4* sw = (float4*)(sbase + (cur ^ 1) * 4 * NPTS);
#pragma unroll
                for (int i = 0; i < 4; i++) sw[i*256 + tid] = pf[i];
                __syncthreads();             // writes visible before next chunk's reads
            }
        }
    } else {
        for (int c = 0; c < C; c++) {
            float ct[R];
#pragma unroll
            for (int rr = 0; rr < R; rr++) ct[rr] = frow[(size_t)(r0+rr) * frs + c];
            const float4* rm = (const float4*)(ftb + (size_t)c * NPTS);
#pragma unroll
            for (int j = 0; j < 4; j++) {
                float4 v = rm[lane + 64*j];
#pragma unroll
                for (int rr = 0; rr < R; rr++) {
                    float cs = ct[rr];
                    acc[rr][j].x = fmaf(cs, v.x, acc[rr][j].x);
                    acc[rr][j].y = fmaf(cs, v.y, acc[rr][j].y);
                    acc[rr][j].z = fmaf(cs, v.z, acc[rr][j].z);
                    acc[rr][j].w = fmaf(cs, v.w, acc[rr][j].w);
                }
            }
        }
    }

    const float4* nm4 = (const float4*)(nrm + b * NPTS);
#pragma unroll
    for (int p = 0; p < R/2; p++)
        select_pair(acc[2*p], acc[2*p+1], nm4, lane, cand[w], r0 + 2*p, r0 + 2*p + 1, idx);
}

// ---- H/Ct GEMM: Ht[n,o]=F.w1; Ct[n,o]=F.w2 - Ht + bias ----
template<int C, int O, bool HASB, int RPB>
__global__ void hc_k(const float* __restrict__ F, int FS,
                     const float* __restrict__ w, const float* __restrict__ bias,
                     float* __restrict__ Ht, float* __restrict__ Ct) {
    int r0 = blockIdx.x * RPB;
    int o = threadIdx.x;
    const float* wr = w + (size_t)o * (2*C);
    float h[RPB], a2[RPB];
#pragma unroll
    for (int nn = 0; nn < RPB; nn++) { h[nn] = 0.f; a2[nn] = 0.f; }
    if constexpr ((C & 3) == 0) {
        const float4* w1 = (const float4*)wr;
        const float4* w2 = (const float4*)(wr + C);
#pragma unroll 4
        for (int c4 = 0; c4 < C/4; c4++) {
            float4 wa = w1[c4], wb = w2[c4];
#pragma unroll
            for (int nn = 0; nn < RPB; nn++) {
                float4 f = *(const float4*)(F + (size_t)(r0+nn)*FS + 4*c4);  // broadcast
                h[nn]  = fmaf(wa.x,f.x, fmaf(wa.y,f.y, fmaf(wa.z,f.z, fmaf(wa.w,f.w, h[nn]))));
                a2[nn] = fmaf(wb.x,f.x, fmaf(wb.y,f.y, fmaf(wb.z,f.z, fmaf(wb.w,f.w, a2[nn]))));
            }
        }
    } else {
        for (int c = 0; c < C; c++) {
            float wa = wr[c], wb = wr[C+c];
#pragma unroll
            for (int nn = 0; nn < RPB; nn++) {
                float f = F[(size_t)(r0+nn)*FS + c];
                h[nn]  = fmaf(wa, f, h[nn]);
                a2[nn] = fmaf(wb, f, a2[nn]);
            }
        }
    }
    float bs = 0.f;
    if constexpr (HASB) bs = bias[o];
#pragma unroll
    for (int nn = 0; nn < RPB; nn++) {
        size_t ro = (size_t)(r0+nn)*O + o;
        Ht[ro] = h[nn];
        Ct[ro] = a2[nn] - h[nn] + bs;
    }
}

// ---- gather + max_k + bn + lrelu; optional transposed-feature + norms for next knn ----
// XCD-swizzled r mapping (R8-validated): batch = blockIdx&7 keeps gathers in-XCD.
template<int O, bool WFT>
__global__ void gmax_k(const float* __restrict__ Ht, const float* __restrict__ Ct,
                       const int* __restrict__ idx,
                       const float* __restrict__ g, const float* __restrict__ bb,
                       float* __restrict__ xcs, float* __restrict__ ft, float* __restrict__ nrm) {
    int b = blockIdx.x & 7;
    int n = blockIdx.x >> 3;
    int r = b * NPTS + n;
    int o = threadIdx.x;
    const int* id = idx + r * KNN;
    float vmax = -INFINITY, vmin = INFINITY;
    const float* hb = Ht + (size_t)b * NPTS * O + o;
#pragma unroll 4
    for (int k = 0; k < KNN; k++) {
        int m = id[k];                 // broadcast
        float v = hb[(size_t)m * O];   // coalesced across o
        vmax = fmaxf(vmax, v); vmin = fminf(vmin, v);
    }
    float ct = Ct[(size_t)r * O + o];
    float s = g[o] * BN_SC;
    float pre = (s >= 0.f ? vmax : vmin) + ct;
    float out = lrelu(fmaf(s, pre, bb[o]));
    xcs[(size_t)r * XC_C + o] = out;
    if constexpr (WFT) {
        ft[((size_t)b * O + o) * NPTS + n] = out;
        float sq = out * out;
#pragma unroll
        for (int off = 32; off > 0; off >>= 1) sq += __shfl_xor(sq, off);
        __shared__ float red[O/64 > 0 ? O/64 : 1];
        if ((o & 63) == 0) red[o >> 6] = sq;
        __syncthreads();
        if (o == 0) {
            float t = 0.f;
#pragma unroll
            for (int i = 0; i < O/64; i++) t += red[i];
            nrm[r] = t;
        }
    }
}

// ---- split-bf16 conversions for conv5 MFMA ----
__global__ void xcvt_k(const float* __restrict__ xc,
                       unsigned short* __restrict__ xh, unsigned short* __restrict__ xl) {
    int i = blockIdx.x * 256 + threadIdx.x;   // BN*512
    float v = xc[i];
    unsigned short h = f2bf(v);
    xh[i] = h;
    xl[i] = f2bf(v - bf2f(h));
}

__global__ void wcvt_k(const float* __restrict__ w5,
                       unsigned short* __restrict__ wh, unsigned short* __restrict__ wl) {
    int i = blockIdx.x * 256 + threadIdx.x;   // 1024*512, (o,c) row-major kept
    float v = w5[i];
    unsigned short h = f2bf(v);
    wh[i] = h;
    wl[i] = f2bf(v - bf2f(h));
}

// ---- conv5 A/B, cutoff-proof: BOTH variants run the FULL grid this round.
// 32-row writes part (real output path); 64-row writes dead scratch. Both therefore
// appear full-size in the profile -> direct within-run comparison, no container noise.
__global__ __launch_bounds__(256) void conv5mfma32_k(const unsigned short* __restrict__ xh,
                                                     const unsigned short* __restrict__ xl,
                                                     const unsigned short* __restrict__ wh,
                                                     const unsigned short* __restrict__ wl,
                                                     float* __restrict__ part) {
    __shared__ short ah_s[32*72];
    __shared__ short al_s[32*72];
    __shared__ short bh_s[128*72];
    __shared__ short bl_s[128*72];
    int b = blockIdx.z, og = blockIdx.y, nt = blockIdx.x;   // nt 0..31
    int tid = threadIdx.x;
    int w = tid >> 6, lane = tid & 63;
    int m = lane & 15, quad = lane >> 4;
    int h = w >> 1, q = w & 1;
    size_t nbase = (size_t)b * NPTS + nt * 32;
    int obase = og * 128;
    int srow = tid >> 3;
    int scol = (tid & 7) * 8;

    floatx4 acc[4];
#pragma unroll
    for (int t = 0; t < 4; t++) acc[t] = (floatx4){0.f, 0.f, 0.f, 0.f};

    for (int kc = 0; kc < 512; kc += 64) {
        short8 pa[2], pb[8];
        pa[0] = *(const short8*)(xh + (nbase + srow)*512 + kc + scol);
        pa[1] = *(const short8*)(xl + (nbase + srow)*512 + kc + scol);
#pragma unroll
        for (int i = 0; i < 4; i++) {
            int r = srow + i*32;
            pb[2*i]   = *(const short8*)(wh + (size_t)(obase + r)*512 + kc + scol);
            pb[2*i+1] = *(const short8*)(wl + (size_t)(obase + r)*512 + kc + scol);
        }
        __syncthreads();
        *(short8*)(ah_s + srow*72 + scol) = pa[0];
        *(short8*)(al_s + srow*72 + scol) = pa[1];
#pragma unroll
        for (int i = 0; i < 4; i++) {
            int r = srow + i*32;
            *(short8*)(bh_s + r*72 + scol) = pb[2*i];
            *(short8*)(bl_s + r*72 + scol) = pb[2*i+1];
        }
        __syncthreads();
#pragma unroll
        for (int kk = 0; kk < 2; kk++) {
            short8 ah8 = *(const short8*)(ah_s + (h*16 + m)*72 + kk*32 + quad*8);
            short8 al8 = *(const short8*)(al_s + (h*16 + m)*72 + kk*32 + quad*8);
#pragma unroll
            for (int t = 0; t < 4; t++) {
                short8 bh8 = *(const short8*)(bh_s + (q*64 + t*16 + m)*72 + kk*32 + quad*8);
                short8 bl8 = *(const short8*)(bl_s + (q*64 + t*16 + m)*72 + kk*32 + quad*8);
                acc[t] = __builtin_amdgcn_mfma_f32_16x16x32_bf16(ah8, bh8, acc[t], 0, 0, 0);
                acc[t] = __builtin_amdgcn_mfma_f32_16x16x32_bf16(ah8, bl8, acc[t], 0, 0, 0);
                acc[t] = __builtin_amdgcn_mfma_f32_16x16x32_bf16(al8, bh8, acc[t], 0, 0, 0);
            }
        }
    }
#pragma unroll
    for (int t = 0; t < 4; t++) {
        float v = fmaxf(fmaxf(acc[t][0], acc[t][1]), fmaxf(acc[t][2], acc[t][3]));
        v = fmaxf(v, __shfl_xor(v, 16));
        v = fmaxf(v, __shfl_xor(v, 32));
        if (quad == 0)
            part[((size_t)b * 64 + nt*2 + h) * 1024 + obase + q*64 + t*16 + m] = v;
    }
}

__global__ __launch_bounds__(256) void conv5mfma64_k(const unsigned short* __restrict__ xh,
                                                     const unsigned short* __restrict__ xl,
                                                     const unsigned short* __restrict__ wh,
                                                     const unsigned short* __restrict__ wl,
                                                     float* __restrict__ part) {
    __shared__ short ah_s[64*72];
    __shared__ short al_s[64*72];
    __shared__ short bh_s[128*72];
    __shared__ short bl_s[128*72];
    int b = blockIdx.z, og = blockIdx.y, nt = blockIdx.x;   // nt 0..15
    int tid = threadIdx.x;
    int w = tid >> 6, lane = tid & 63;
    int m = lane & 15, quad = lane >> 4;
    int h = w >> 1, q = w & 1;
    size_t nbase = (size_t)b * NPTS + nt * 64;
    int obase = og * 128;
    int srow = tid >> 3;
    int scol = (tid & 7) * 8;

    floatx4 acc[2][4];
#pragma unroll
    for (int i = 0; i < 2; i++)
#pragma unroll
        for (int t = 0; t < 4; t++) acc[i][t] = (floatx4){0.f, 0.f, 0.f, 0.f};

    for (int kc = 0; kc < 512; kc += 64) {
        short8 pa[4], pb[8];
        pa[0] = *(const short8*)(xh + (nbase + srow)*512 + kc + scol);
        pa[1] = *(const short8*)(xl + (nbase + srow)*512 + kc + scol);
        pa[2] = *(const short8*)(xh + (nbase + 32 + srow)*512 + kc + scol);
        pa[3] = *(const short8*)(xl + (nbase + 32 + srow)*512 + kc + scol);
#pragma unroll
        for (int i = 0; i < 4; i++) {
            int r = srow + i*32;
            pb[2*i]   = *(const short8*)(wh + (size_t)(obase + r)*512 + kc + scol);
            pb[2*i+1] = *(const short8*)(wl + (size_t)(obase + r)*512 + kc + scol);
        }
        __syncthreads();
        *(short8*)(ah_s + srow*72 + scol)      = pa[0];
        *(short8*)(al_s + srow*72 + scol)      = pa[1];
        *(short8*)(ah_s + (32+srow)*72 + scol) = pa[2];
        *(short8*)(al_s + (32+srow)*72 + scol) = pa[3];
#pragma unroll
        for (int i = 0; i < 4; i++) {
            int r = srow + i*32;
            *(short8*)(bh_s + r*72 + scol) = pb[2*i];
            *(short8*)(bl_s + r*72 + scol) = pb[2*i+1];
        }
        __syncthreads();
#pragma unroll
        for (int kk = 0; kk < 2; kk++) {
            short8 ah8[2], al8[2];
#pragma unroll
            for (int i = 0; i < 2; i++) {
                ah8[i] = *(const short8*)(ah_s + (i*32 + h*16 + m)*72 + kk*32 + quad*8);
                al8[i] = *(const short8*)(al_s + (i*32 + h*16 + m)*72 + kk*32 + quad*8);
            }
#pragma unroll
            for (int t = 0; t < 4; t++) {
                short8 bh8 = *(const short8*)(bh_s + (q*64 + t*16 + m)*72 + kk*32 + quad*8);
                short8 bl8 = *(const short8*)(bl_s + (q*64 + t*16 + m)*72 + kk*32 + quad*8);
#pragma unroll
                for (int i = 0; i < 2; i++) {
                    acc[i][t] = __builtin_amdgcn_mfma_f32_16x16x32_bf16(ah8[i], bh8, acc[i][t], 0, 0, 0);
                    acc[i][t] = __builtin_amdgcn_mfma_f32_16x16x32_bf16(ah8[i], bl8, acc[i][t], 0, 0, 0);
                    acc[i][t] = __builtin_amdgcn_mfma_f32_16x16x32_bf16(al8[i], bh8, acc[i][t], 0, 0, 0);
                }
            }
        }
    }
#pragma unroll
    for (int i = 0; i < 2; i++)
#pragma unroll
    for (int t = 0; t < 4; t++) {
        float v = fmaxf(fmaxf(acc[i][t][0], acc[i][t][1]), fmaxf(acc[i][t][2], acc[i][t][3]));
        v = fmaxf(v, __shfl_xor(v, 16));
        v = fmaxf(v, __shfl_xor(v, 32));
        if (quad == 0)
            part[((size_t)b * 64 + nt*4 + i*2 + h) * 1024 + obase + q*64 + t*16 + m] = v;
    }
}

// ---- global max pool: gp[b,o] = max_j part[b,j,o] ----
__global__ void gpool_k(const float* __restrict__ part, float* __restrict__ gp) {
    int i = blockIdx.x * 256 + threadIdx.x;   // b*1024+o
    int b = i >> 10, o = i & 1023;
    const float* pb = part + (size_t)b * 64 * 1024 + o;
    float m = pb[0];
#pragma unroll 4
    for (int j = 1; j < 64; j++) m = fmaxf(m, pb[(size_t)j * 1024]);
    gp[i] = m;
}

// ---- linear layer, one wave per output dot ----
template<int C, bool HASBIAS, bool ACT>
__global__ __launch_bounds__(256) void lin_k(const float* __restrict__ X, int xs,
                                             const float* __restrict__ W,
                                             const float* __restrict__ bias,
                                             const float* __restrict__ g, const float* __restrict__ bb,
                                             float* __restrict__ Y, int ys) {
    int wid = (blockIdx.x * 256 + threadIdx.x) >> 6;
    int lane = threadIdx.x & 63;
    int o = wid >> 3;          // NB = 8
    int b = wid & 7;
    const float4* wr = (const float4*)(W + (size_t)o * C);
    const float4* xr = (const float4*)(X + (size_t)b * xs);
    float acc = 0.f;
#pragma unroll
    for (int i = 0; i < C/256; i++) {
        float4 w = wr[lane + 64*i];
        float4 xv = xr[lane + 64*i];
        acc = fmaf(w.x,xv.x, fmaf(w.y,xv.y, fmaf(w.z,xv.z, fmaf(w.w,xv.w, acc))));
    }
#pragma unroll
    for (int off = 32; off > 0; off >>= 1) acc += __shfl_xor(acc, off);
    if (lane == 0) {
        if constexpr (HASBIAS) acc += bias[o];
        if constexpr (ACT) acc = lrelu(fmaf(acc, g[o] * BN_SC, bb[o]));
        Y[(size_t)b * ys + o] = acc;
    }
}

extern "C" void kernel_launch(void* const* d_in, const int* in_sizes, int n_in,
                              void* d_out, int out_size, void* d_ws, size_t ws_size,
                              hipStream_t stream) {
    const float* x       = (const float*)d_in[0];
    const float* conv1_w = (const float*)d_in[1];
    const float* conv1_b = (const float*)d_in[2];
    const float* bn1_g   = (const float*)d_in[3];
    const float* bn1_b   = (const float*)d_in[4];
    const float* conv2_w = (const float*)d_in[5];
    const float* bn2_g   = (const float*)d_in[6];
    const float* bn2_b   = (const float*)d_in[7];
    const float* conv3_w = (const float*)d_in[8];
    const float* bn3_g   = (const float*)d_in[9];
    const float* bn3_b   = (const float*)d_in[10];
    const float* conv4_w = (const float*)d_in[11];
    const float* bn4_g   = (const float*)d_in[12];
    const float* bn4_b   = (const float*)d_in[13];
    const float* conv5_w = (const float*)d_in[14];
    const float* lin1_w  = (const float*)d_in[15];
    const float* bn6_g   = (const float*)d_in[16];
    const float* bn6_b   = (const float*)d_in[17];
    const float* lin2_w  = (const float*)d_in[18];
    const float* lin2_b  = (const float*)d_in[19];
    const float* bn7_g   = (const float*)d_in[20];
    const float* bn7_b   = (const float*)d_in[21];
    const float* lin3_w  = (const float*)d_in[22];
    const float* lin3_b  = (const float*)d_in[23];
    float* outp = (float*)d_out;

    // workspace layout (floats): total 10,657,792 f = 42.6 MB
    float* ws   = (float*)d_ws;
    float* xc   = ws;                          // (BN,512)          4,194,304
    int*   idxb = (int*)(ws + 4194304);        // (BN,20)             163,840
    float* nrm  = ws + 4194304 + 163840;       // (BN)                  8,192
    float* ft   = nrm + 8192;                  // (B,<=128,N)       1,048,576
    float* part = ft + 1048576;                // (B,64,1024)         524,288
    float* w5t  = part + 524288;               // bf16 wh/wl          524,288
    float* Ht   = w5t + 524288;                // (BN,<=256) / xh   2,097,152
    float* Ct   = Ht + 2097152;                // (BN,<=256) / xl   2,097,152
    // head scratch aliases ft (dead after the last knn_k):
    float* gp   = ft;                          // (8,1024)
    float* y1   = ft + 8192;                   // (8,512)
    float* y2   = ft + 8192 + 4096;            // (8,256)
    float* pdup = ft + 16384;                  // (8,64,1024) dead A/B scratch (fits: 16384+524288 < 1048576)
    // split-bf16 aliases (dead regions after stage 4):
    unsigned short* xhp = (unsigned short*)Ht;       // BN*512 shorts
    unsigned short* xlp = (unsigned short*)Ct;
    unsigned short* whp = (unsigned short*)w5t;      // 1024*512 shorts
    unsigned short* wlp = whp + 1024*512;

    prep_k<<<BN/256, 256, 0, stream>>>(x, ft, nrm);

    // Stage 1: C=3 (coords), O=64, with conv bias; R=4 + XCD swizzle
    knn_k<3, 4><<<BN/16, 256, 0, stream>>>(ft, x, 3, nrm, idxb);
    hc_k<3, 64, true, 4><<<BN/4, 64, 0, stream>>>(x, 3, conv1_w, conv1_b, Ht, Ct);
    gmax_k<64, true><<<BN, 64, 0, stream>>>(Ht, Ct, idxb, bn1_g, bn1_b, xc + 0, ft, nrm);

    // Stage 2: C=64 -> O=64; LDS-staged m-stream (R10 pipeline)
    knn_k<64, 4><<<BN/16, 256, 0, stream>>>(ft, xc + 0, XC_C, nrm, idxb);
    hc_k<64, 64, false, 4><<<BN/4, 64, 0, stream>>>(xc + 0, XC_C, conv2_w, nullptr, Ht, Ct);
    gmax_k<64, true><<<BN, 64, 0, stream>>>(Ht, Ct, idxb, bn2_g, bn2_b, xc + 64, ft, nrm);

    // Stage 3: C=64 -> O=128
    knn_k<64, 4><<<BN/16, 256, 0, stream>>>(ft, xc + 64, XC_C, nrm, idxb);
    hc_k<64, 128, false, 4><<<BN/4, 128, 0, stream>>>(xc + 64, XC_C, conv3_w, nullptr, Ht, Ct);
    gmax_k<128, true><<<BN, 128, 0, stream>>>(Ht, Ct, idxb, bn3_g, bn3_b, xc + 128, ft, nrm);

    // Stage 4: C=128 -> O=256 (no next knn)
    knn_k<128, 4><<<BN/16, 256, 0, stream>>>(ft, xc + 128, XC_C, nrm, idxb);
    hc_k<128, 256, false, 8><<<BN/8, 256, 0, stream>>>(xc + 128, XC_C, conv4_w, nullptr, Ht, Ct);
    gmax_k<256, false><<<BN, 256, 0, stream>>>(Ht, Ct, idxb, bn4_g, bn4_b, xc + 256, nullptr, nullptr);

    // conv5 A/B (one diagnostic round): 32-row full grid -> part (real);
    // 64-row full grid -> dead scratch. Both full-size => both visible in profile.
    xcvt_k<<<BN*512/256, 256, 0, stream>>>(xc, xhp, xlp);
    wcvt_k<<<1024*512/256, 256, 0, stream>>>(conv5_w, whp, wlp);
    conv5mfma32_k<<<dim3(32, 8, NB), 256, 0, stream>>>(xhp, xlp, whp, wlp, part);
    conv5mfma64_k<<<dim3(16, 8, NB), 256, 0, stream>>>(xhp, xlp, whp, wlp, pdup);
    gpool_k<<<NB*1024/256, 256, 0, stream>>>(part, gp);
    lin_k<1024, false, true><<<NB*512/4, 256, 0, stream>>>(gp, 1024, lin1_w, nullptr, bn6_g, bn6_b, y1, 512);
    lin_k<512,  true,  true><<<NB*256/4, 256, 0, stream>>>(y1, 512, lin2_w, lin2_b, bn7_g, bn7_b, y2, 256);
    lin_k<256,  true, false><<<NB*40/4,  256, 0, stream>>>(y2, 256, lin3_w, lin3_b, nullptr, nullptr, outp, 40);
}

// Round 14
// 427.479 us; speedup vs baseline: 1.2219x; 1.0850x over previous
//
#include <hip/hip_runtime.h>
#include <cmath>
#include <cstdint>
#include <cstddef>

#define NB 8
#define NPTS 1024
#define BN (NB*NPTS)
#define KNN 20
#define XC_C 512
#define BN_SC 0.99999500003749973f  // 1/sqrt(1+1e-5)

static __device__ __forceinline__ float lrelu(float z) { return z >= 0.f ? z : 0.01f * z; }

// Interleaved DPP max step for TWO independent (lo,hi) u64 chains — R2/R12-validated on HW.
// (Used only by the rare fallback path.)
template<int CTRL>
static __device__ __forceinline__ void dpp_max2(unsigned& loA, unsigned& hiA,
                                                unsigned& loB, unsigned& hiB) {
    unsigned tlA = (unsigned)__builtin_amdgcn_update_dpp(0, (int)loA, CTRL, 0xF, 0xF, false);
    unsigned thA = (unsigned)__builtin_amdgcn_update_dpp(0, (int)hiA, CTRL, 0xF, 0xF, false);
    unsigned tlB = (unsigned)__builtin_amdgcn_update_dpp(0, (int)loB, CTRL, 0xF, 0xF, false);
    unsigned thB = (unsigned)__builtin_amdgcn_update_dpp(0, (int)hiB, CTRL, 0xF, 0xF, false);
    unsigned long long a = ((unsigned long long)hiA << 32) | loA;
    unsigned long long b = ((unsigned long long)thA << 32) | tlA;
    if (b > a) { loA = tlA; hiA = thA; }
    unsigned long long c = ((unsigned long long)hiB << 32) | loB;
    unsigned long long d = ((unsigned long long)thB << 32) | tlB;
    if (d > c) { loB = tlB; hiB = thB; }
}

static __device__ __forceinline__ void wave_max_u64_x2(unsigned long long vA, unsigned long long vB,
                                                       unsigned long long& winA, unsigned long long& winB) {
    unsigned loA = (unsigned)vA, hiA = (unsigned)(vA >> 32);
    unsigned loB = (unsigned)vB, hiB = (unsigned)(vB >> 32);
    dpp_max2<0x121>(loA, hiA, loB, hiB);
    dpp_max2<0x122>(loA, hiA, loB, hiB);
    dpp_max2<0x124>(loA, hiA, loB, hiB);
    dpp_max2<0x128>(loA, hiA, loB, hiB);
    dpp_max2<0x142>(loA, hiA, loB, hiB);   // row_bcast15
    dpp_max2<0x143>(loA, hiA, loB, hiB);   // row_bcast31; lane63 = wave max
    unsigned wloA = (unsigned)__builtin_amdgcn_readlane((int)loA, 63);
    unsigned whiA = (unsigned)__builtin_amdgcn_readlane((int)hiA, 63);
    unsigned wloB = (unsigned)__builtin_amdgcn_readlane((int)loB, 63);
    unsigned whiB = (unsigned)__builtin_amdgcn_readlane((int)hiB, 63);
    winA = ((unsigned long long)whiA << 32) | wloA;
    winB = ((unsigned long long)whiB << 32) | wloB;
}

// ---- cross-lane helpers for the threshold-prune selection path (R1-validated) ----
static __device__ __forceinline__ unsigned long long shflx64(unsigned long long v, int m) {
    int lo = __shfl_xor((int)(unsigned)v, m);
    int hi = __shfl_xor((int)(unsigned)(v >> 32), m);
    return ((unsigned long long)(unsigned)hi << 32) | (unsigned)lo;
}

static __device__ __forceinline__ unsigned long long rdlane64(unsigned long long v, int l) {
    unsigned lo = (unsigned)__builtin_amdgcn_readlane((int)(unsigned)v, l);
    unsigned hi = (unsigned)__builtin_amdgcn_readlane((int)(unsigned)(v >> 32), l);
    return ((unsigned long long)hi << 32) | lo;
}

// 64-lane bitonic sort, descending, TWO independent u64 chains interleaved for ILP.
static __device__ __forceinline__ void bitonic64_desc_x2(unsigned long long& vA,
                                                         unsigned long long& vB, int lane) {
#pragma unroll
    for (int k = 2; k <= 64; k <<= 1) {
#pragma unroll
        for (int j = k >> 1; j > 0; j >>= 1) {
            unsigned long long pA = shflx64(vA, j);
            unsigned long long pB = shflx64(vB, j);
            bool takeMax = (((lane & k) == 0) == ((lane & j) == 0));
            vA = ((pA > vA) == takeMax) ? pA : vA;
            vB = ((pB > vB) == takeMax) ? pB : vB;
        }
    }
}

// ---- R1/R5-validated selection for a pair of rows, from their distance accumulators. ----
static __device__ __forceinline__ void select_pair(const float4* accA, const float4* accB,
                                                   const float4* nm4, int lane,
                                                   unsigned long long (*cw)[64],
                                                   int rA, int rB, int* __restrict__ idx) {
    unsigned long long keyA[16], keyB[16];
#pragma unroll
    for (int j = 0; j < 4; j++) {
        float4 nm = nm4[lane + 64*j];
#pragma unroll
        for (int q = 0; q < 4; q++) {
            int m = 4*(lane + 64*j) + q;
            float fA = 2.f * (&accA[j].x)[q] - (&nm.x)[q];
            unsigned uA = __float_as_uint(fA);
            unsigned sA_ = (unsigned)((int)uA >> 31);
            uA ^= (sA_ | 0x80000000u);
            keyA[4*j+q] = ((unsigned long long)uA << 32) | (unsigned)(1023 - m);
            float fB = 2.f * (&accB[j].x)[q] - (&nm.x)[q];
            unsigned uB = __float_as_uint(fB);
            unsigned sB_ = (unsigned)((int)uB >> 31);
            uB ^= (sB_ | 0x80000000u);
            keyB[4*j+q] = ((unsigned long long)uB << 32) | (unsigned)(1023 - m);
        }
    }

    // per-lane heads
    unsigned long long hA = keyA[0], hB = keyB[0];
#pragma unroll
    for (int i = 1; i < 16; i++) {
        hA = keyA[i] > hA ? keyA[i] : hA;
        hB = keyB[i] > hB ? keyB[i] : hB;
    }

    // L = 20th largest head
    unsigned long long shA = hA, shB = hB;
    bitonic64_desc_x2(shA, shB, lane);
    unsigned long long LA = rdlane64(shA, KNN - 1);
    unsigned long long LB = rdlane64(shB, KNN - 1);

    // count + wave prefix scan
    int cA = 0, cB = 0;
#pragma unroll
    for (int i = 0; i < 16; i++) {
        cA += (keyA[i] >= LA) ? 1 : 0;
        cB += (keyB[i] >= LB) ? 1 : 0;
    }
    int sA = cA, sB = cB;
#pragma unroll
    for (int off = 1; off < 64; off <<= 1) {
        int tA = __shfl_up(sA, off);
        int tB = __shfl_up(sB, off);
        if (lane >= off) { sA += tA; sB += tB; }
    }
    int totA = __builtin_amdgcn_readlane(sA, 63);     // wave-uniform
    int totB = __builtin_amdgcn_readlane(sB, 63);
    int pA = sA - cA, pB = sB - cB;                   // exclusive prefix

    if (totA <= 64 && totB <= 64) {
        int wa = pA, wb = pB;
#pragma unroll
        for (int i = 0; i < 16; i++) {
            if (keyA[i] >= LA) cw[0][wa++] = keyA[i];
            if (keyB[i] >= LB) cw[1][wb++] = keyB[i];
        }
        // same-wave LDS RAW: drain lgkm before reads, block compile-time motion.
        asm volatile("s_waitcnt lgkmcnt(0)" ::: "memory");
        unsigned long long vA = 0ull, vB = 0ull;
        if (lane < totA) vA = cw[0][lane];
        if (lane < totB) vB = cw[1][lane];
        bitonic64_desc_x2(vA, vB, lane);              // sentinels to back; tot >= 20 always
        if (lane < KNN) {
            idx[rA * KNN + lane] = 1023 - (int)(unsigned)vA;
            idx[rB * KNN + lane] = 1023 - (int)(unsigned)vB;
        }
    } else {
        // fallback: per-lane bitonic sort + 20-round DPP pop (wave-uniform branch).
#pragma unroll
        for (int ksz = 2; ksz <= 16; ksz <<= 1) {
#pragma unroll
            for (int jst = ksz >> 1; jst > 0; jst >>= 1) {
#pragma unroll
                for (int i = 0; i < 16; i++) {
                    int l = i ^ jst;
                    if (l > i) {
                        bool dsc = (i & ksz) == 0;
                        unsigned long long a = keyA[i], bbv = keyA[l];
                        bool swA = dsc ? (a < bbv) : (a > bbv);
                        if (swA) { keyA[i] = bbv; keyA[l] = a; }
                        unsigned long long c = keyB[i], d = keyB[l];
                        bool swB = dsc ? (c < d) : (c > d);
                        if (swB) { keyB[i] = d; keyB[l] = c; }
                    }
                }
            }
        }
        int mineA = 0, mineB = 0;
        for (int kk = 0; kk < KNN; kk++) {       // not unrolled
            unsigned long long winA, winB;
            wave_max_u64_x2(keyA[0], keyB[0], winA, winB);
            if (lane == kk) {
                mineA = 1023 - (int)(unsigned)winA;
                mineB = 1023 - (int)(unsigned)winB;
            }
            bool popA = (keyA[0] == winA);
            bool popB = (keyB[0] == winB);
#pragma unroll
            for (int t = 0; t < 15; t++) {
                keyA[t] = popA ? keyA[t+1] : keyA[t];
                keyB[t] = popB ? keyB[t+1] : keyB[t];
            }
            keyA[15] = popA ? 0ull : keyA[15];
            keyB[15] = popB ? 0ull : keyB[15];
        }
        if (lane < KNN) {
            idx[rA * KNN + lane] = mineA;
            idx[rB * KNN + lane] = mineB;
        }
    }
}

// ---- bf16 split helpers (RNE) ----
static __device__ __forceinline__ unsigned short f2bf(float f) {
    unsigned u = __float_as_uint(f);
    unsigned r = u + 0x7fffu + ((u >> 16) & 1u);
    return (unsigned short)(r >> 16);
}
static __device__ __forceinline__ float bf2f(unsigned short h) {
    return __uint_as_float(((unsigned)h) << 16);
}

typedef __attribute__((ext_vector_type(8))) short short8;
typedef __attribute__((ext_vector_type(4))) float floatx4;

// ---- prep: x (B,N,3) -> ft (B,3,N) + norms ----
__global__ void prep_k(const float* __restrict__ x, float* __restrict__ ft, float* __restrict__ nrm) {
    int i = blockIdx.x * 256 + threadIdx.x;   // b*N+n
    if (i >= BN) return;
    int b = i >> 10, n = i & 1023;
    float a = x[3*i], c = x[3*i+1], d = x[3*i+2];
    float* fb = ft + (size_t)b * 3 * NPTS;
    fb[n] = a; fb[NPTS + n] = c; fb[2*NPTS + n] = d;
    nrm[i] = a*a + c*c + d*d;
}

// ---- fused knn, R=2 rows/wave, XCD swizzle, LDS-staged m-stream (R10 pipeline).
// R13 POST-MORTEM: knn is GRID-limited — occupancy 20% = 2 blocks/CU x 4 waves
// (grid 512 on 256 CUs). VGPR 128 allows 4 waves/SIMD; LDS 36KB allows 4 blocks/CU;
// neither binds. FIX: R=2 -> grid 1024 -> 4 blocks/CU = 16 waves/CU (50%): 2x the
// latency-hiding TLP. acc halves (32 regs) so VGPR stays <= 128 (the 4-wave/SIMD
// step). Staging is per-block (unchanged); per-row fmaf chain order byte-identical
// -> same keys -> same idx -> absmax 0.0. sbuf size-conditional (C=3 carries no LDS).
template<int C, int R>
__global__ __launch_bounds__(256, 2) void knn_k(const float* __restrict__ ft,
                                                const float* __restrict__ frow, int frs,
                                                const float* __restrict__ nrm,
                                                int* __restrict__ idx) {
    __shared__ unsigned long long cand[4][2][64];   // 4 KB: per-wave, per-row candidate slots
    __shared__ float sbuf[((C & 3) == 0) ? 2 * 4 * NPTS : 1];   // 32 KB staged / 4 B unused
    int tid = threadIdx.x;
    int w = tid >> 6;
    int lane = tid & 63;
    int b    = blockIdx.x & 7;              // batch == XCD (round-robin dispatch heuristic)
    int slot = blockIdx.x >> 3;             // row-block within batch
    int r0 = b * NPTS + slot * (4*R) + R * w;   // R consecutive rows per wave
    const float* ftb = ft + (size_t)b * C * NPTS;

    float4 acc[R][4];
#pragma unroll
    for (int rr = 0; rr < R; rr++)
#pragma unroll
        for (int j = 0; j < 4; j++) acc[rr][j] = make_float4(0.f,0.f,0.f,0.f);

    if constexpr ((C & 3) == 0) {
        constexpr int NC = C / 4;
        const float4* cr0 = (const float4*)(frow + (size_t)r0 * frs);
        int frs4 = frs >> 2;
        const float4* src4 = (const float4*)ftb;     // channel c = 256 float4 row
        float* sbase = &sbuf[0];
        float4 pf[4];
        // prologue: stage chunk 0 (channels 0..3) -> buf0
#pragma unroll
        for (int i = 0; i < 4; i++) pf[i] = src4[i*256 + tid];
        {
            float4* sw = (float4*)sbase;
#pragma unroll
            for (int i = 0; i < 4; i++) sw[i*256 + tid] = pf[i];
        }
        __syncthreads();
        for (int c4 = 0; c4 < NC; c4++) {
            int cur = c4 & 1;
            if (c4 + 1 < NC) {               // issue next chunk's global loads early
#pragma unroll
                for (int i = 0; i < 4; i++) pf[i] = src4[(size_t)(4*(c4+1)+i)*256 + tid];
            }
            float4 ct[R];
#pragma unroll
            for (int rr = 0; rr < R; rr++) ct[rr] = cr0[c4 + rr*frs4];
            const float4* sc = (const float4*)(sbase + cur * 4 * NPTS);
#pragma unroll
            for (int cc = 0; cc < 4; cc++) {
                const float4* rm = sc + cc*256;
#pragma unroll
                for (int j = 0; j < 4; j++) {
                    float4 v = rm[lane + 64*j];          // LDS, lane-consecutive: conflict-free
#pragma unroll
                    for (int rr = 0; rr < R; rr++) {
                        float cs = (&ct[rr].x)[cc];
                        acc[rr][j].x = fmaf(cs, v.x, acc[rr][j].x);
                        acc[rr][j].y = fmaf(cs, v.y, acc[rr][j].y);
                        acc[rr][j].z = fmaf(cs, v.z, acc[rr][j].z);
                        acc[rr][j].w = fmaf(cs, v.w, acc[rr][j].w);
                    }
                }
            }
            if (c4 + 1 < NC) {
                // write next chunk to the other buffer: its readers (chunk c4-1)
                // all passed the previous barrier -> safe without a pre-write sync.
                float4* sw = (float4*)(sbase + (cur ^ 1) * 4 * NPTS);
#pragma unroll
                for (int i = 0; i < 4; i++) sw[i*256 + tid] = pf[i];
                __syncthreads();             // writes visible before next chunk's reads
            }
        }
    } else {
        for (int c = 0; c < C; c++) {
            float ct[R];
#pragma unroll
            for (int rr = 0; rr < R; rr++) ct[rr] = frow[(size_t)(r0+rr) * frs + c];
            const float4* rm = (const float4*)(ftb + (size_t)c * NPTS);
#pragma unroll
            for (int j = 0; j < 4; j++) {
                float4 v = rm[lane + 64*j];
#pragma unroll
                for (int rr = 0; rr < R; rr++) {
                    float cs = ct[rr];
                    acc[rr][j].x = fmaf(cs, v.x, acc[rr][j].x);
                    acc[rr][j].y = fmaf(cs, v.y, acc[rr][j].y);
                    acc[rr][j].z = fmaf(cs, v.z, acc[rr][j].z);
                    acc[rr][j].w = fmaf(cs, v.w, acc[rr][j].w);
                }
            }
        }
    }

    const float4* nm4 = (const float4*)(nrm + b * NPTS);
#pragma unroll
    for (int p = 0; p < R/2; p++)
        select_pair(acc[2*p], acc[2*p+1], nm4, lane, cand[w], r0 + 2*p, r0 + 2*p + 1, idx);
}

// ---- H/Ct GEMM: Ht[n,o]=F.w1; Ct[n,o]=F.w2 - Ht + bias ----
template<int C, int O, bool HASB, int RPB>
__global__ void hc_k(const float* __restrict__ F, int FS,
                     const float* __restrict__ w, const float* __restrict__ bias,
                     float* __restrict__ Ht, float* __restrict__ Ct) {
    int r0 = blockIdx.x * RPB;
    int o = threadIdx.x;
    const float* wr = w + (size_t)o * (2*C);
    float h[RPB], a2[RPB];
#pragma unroll
    for (int nn = 0; nn < RPB; nn++) { h[nn] = 0.f; a2[nn] = 0.f; }
    if constexpr ((C & 3) == 0) {
        const float4* w1 = (const float4*)wr;
        const float4* w2 = (const float4*)(wr + C);
#pragma unroll 4
        for (int c4 = 0; c4 < C/4; c4++) {
            float4 wa = w1[c4], wb = w2[c4];
#pragma unroll
            for (int nn = 0; nn < RPB; nn++) {
                float4 f = *(const float4*)(F + (size_t)(r0+nn)*FS + 4*c4);  // broadcast
                h[nn]  = fmaf(wa.x,f.x, fmaf(wa.y,f.y, fmaf(wa.z,f.z, fmaf(wa.w,f.w, h[nn]))));
                a2[nn] = fmaf(wb.x,f.x, fmaf(wb.y,f.y, fmaf(wb.z,f.z, fmaf(wb.w,f.w, a2[nn]))));
            }
        }
    } else {
        for (int c = 0; c < C; c++) {
            float wa = wr[c], wb = wr[C+c];
#pragma unroll
            for (int nn = 0; nn < RPB; nn++) {
                float f = F[(size_t)(r0+nn)*FS + c];
                h[nn]  = fmaf(wa, f, h[nn]);
                a2[nn] = fmaf(wb, f, a2[nn]);
            }
        }
    }
    float bs = 0.f;
    if constexpr (HASB) bs = bias[o];
#pragma unroll
    for (int nn = 0; nn < RPB; nn++) {
        size_t ro = (size_t)(r0+nn)*O + o;
        Ht[ro] = h[nn];
        Ct[ro] = a2[nn] - h[nn] + bs;
    }
}

// ---- gather + max_k + bn + lrelu; optional transposed-feature + norms for next knn ----
// XCD-swizzled r mapping (R8-validated): batch = blockIdx&7 keeps gathers in-XCD.
template<int O, bool WFT>
__global__ void gmax_k(const float* __restrict__ Ht, const float* __restrict__ Ct,
                       const int* __restrict__ idx,
                       const float* __restrict__ g, const float* __restrict__ bb,
                       float* __restrict__ xcs, float* __restrict__ ft, float* __restrict__ nrm) {
    int b = blockIdx.x & 7;
    int n = blockIdx.x >> 3;
    int r = b * NPTS + n;
    int o = threadIdx.x;
    const int* id = idx + r * KNN;
    float vmax = -INFINITY, vmin = INFINITY;
    const float* hb = Ht + (size_t)b * NPTS * O + o;
#pragma unroll 4
    for (int k = 0; k < KNN; k++) {
        int m = id[k];                 // broadcast
        float v = hb[(size_t)m * O];   // coalesced across o
        vmax = fmaxf(vmax, v); vmin = fminf(vmin, v);
    }
    float ct = Ct[(size_t)r * O + o];
    float s = g[o] * BN_SC;
    float pre = (s >= 0.f ? vmax : vmin) + ct;
    float out = lrelu(fmaf(s, pre, bb[o]));
    xcs[(size_t)r * XC_C + o] = out;
    if constexpr (WFT) {
        ft[((size_t)b * O + o) * NPTS + n] = out;
        float sq = out * out;
#pragma unroll
        for (int off = 32; off > 0; off >>= 1) sq += __shfl_xor(sq, off);
        __shared__ float red[O/64 > 0 ? O/64 : 1];
        if ((o & 63) == 0) red[o >> 6] = sq;
        __syncthreads();
        if (o == 0) {
            float t = 0.f;
#pragma unroll
            for (int i = 0; i < O/64; i++) t += red[i];
            nrm[r] = t;
        }
    }
}

// ---- split-bf16 conversions for conv5 MFMA ----
__global__ void xcvt_k(const float* __restrict__ xc,
                       unsigned short* __restrict__ xh, unsigned short* __restrict__ xl) {
    int i = blockIdx.x * 256 + threadIdx.x;   // BN*512
    float v = xc[i];
    unsigned short h = f2bf(v);
    xh[i] = h;
    xl[i] = f2bf(v - bf2f(h));
}

__global__ void wcvt_k(const float* __restrict__ w5,
                       unsigned short* __restrict__ wh, unsigned short* __restrict__ wl) {
    int i = blockIdx.x * 256 + threadIdx.x;   // 1024*512, (o,c) row-major kept
    float v = w5[i];
    unsigned short h = f2bf(v);
    wh[i] = h;
    wl[i] = f2bf(v - bf2f(h));
}

// ---- conv5 via LDS-staged split-bf16 MFMA (32-row tile, R10-proven 48us) + T14 hoist ----
__global__ __launch_bounds__(256) void conv5mfma_k(const unsigned short* __restrict__ xh,
                                                   const unsigned short* __restrict__ xl,
                                                   const unsigned short* __restrict__ wh,
                                                   const unsigned short* __restrict__ wl,
                                                   float* __restrict__ part) {
    __shared__ short ah_s[32*72];
    __shared__ short al_s[32*72];
    __shared__ short bh_s[128*72];
    __shared__ short bl_s[128*72];
    int b = blockIdx.z, og = blockIdx.y, nt = blockIdx.x;   // nt 0..31
    int tid = threadIdx.x;
    int w = tid >> 6, lane = tid & 63;
    int m = lane & 15, quad = lane >> 4;
    int h = w >> 1, q = w & 1;
    size_t nbase = (size_t)b * NPTS + nt * 32;
    int obase = og * 128;
    int srow = tid >> 3;
    int scol = (tid & 7) * 8;

    floatx4 acc[4];
#pragma unroll
    for (int t = 0; t < 4; t++) acc[t] = (floatx4){0.f, 0.f, 0.f, 0.f};

    for (int kc = 0; kc < 512; kc += 64) {
        short8 pa[2], pb[8];
        pa[0] = *(const short8*)(xh + (nbase + srow)*512 + kc + scol);
        pa[1] = *(const short8*)(xl + (nbase + srow)*512 + kc + scol);
#pragma unroll
        for (int i = 0; i < 4; i++) {
            int r = srow + i*32;
            pb[2*i]   = *(const short8*)(wh + (size_t)(obase + r)*512 + kc + scol);
            pb[2*i+1] = *(const short8*)(wl + (size_t)(obase + r)*512 + kc + scol);
        }
        __syncthreads();
        *(short8*)(ah_s + srow*72 + scol) = pa[0];
        *(short8*)(al_s + srow*72 + scol) = pa[1];
#pragma unroll
        for (int i = 0; i < 4; i++) {
            int r = srow + i*32;
            *(short8*)(bh_s + r*72 + scol) = pb[2*i];
            *(short8*)(bl_s + r*72 + scol) = pb[2*i+1];
        }
        __syncthreads();
#pragma unroll
        for (int kk = 0; kk < 2; kk++) {
            short8 ah8 = *(const short8*)(ah_s + (h*16 + m)*72 + kk*32 + quad*8);
            short8 al8 = *(const short8*)(al_s + (h*16 + m)*72 + kk*32 + quad*8);
#pragma unroll
            for (int t = 0; t < 4; t++) {
                short8 bh8 = *(const short8*)(bh_s + (q*64 + t*16 + m)*72 + kk*32 + quad*8);
                short8 bl8 = *(const short8*)(bl_s + (q*64 + t*16 + m)*72 + kk*32 + quad*8);
                acc[t] = __builtin_amdgcn_mfma_f32_16x16x32_bf16(ah8, bh8, acc[t], 0, 0, 0);
                acc[t] = __builtin_amdgcn_mfma_f32_16x16x32_bf16(ah8, bl8, acc[t], 0, 0, 0);
                acc[t] = __builtin_amdgcn_mfma_f32_16x16x32_bf16(al8, bh8, acc[t], 0, 0, 0);
            }
        }
    }
#pragma unroll
    for (int t = 0; t < 4; t++) {
        float v = fmaxf(fmaxf(acc[t][0], acc[t][1]), fmaxf(acc[t][2], acc[t][3]));
        v = fmaxf(v, __shfl_xor(v, 16));
        v = fmaxf(v, __shfl_xor(v, 32));
        if (quad == 0)
            part[((size_t)b * 64 + nt*2 + h) * 1024 + obase + q*64 + t*16 + m] = v;
    }
}

// ---- global max pool: gp[b,o] = max_j part[b,j,o] ----
__global__ void gpool_k(const float* __restrict__ part, float* __restrict__ gp) {
    int i = blockIdx.x * 256 + threadIdx.x;   // b*1024+o
    int b = i >> 10, o = i & 1023;
    const float* pb = part + (size_t)b * 64 * 1024 + o;
    float m = pb[0];
#pragma unroll 4
    for (int j = 1; j < 64; j++) m = fmaxf(m, pb[(size_t)j * 1024]);
    gp[i] = m;
}

// ---- linear layer, one wave per output dot ----
template<int C, bool HASBIAS, bool ACT>
__global__ __launch_bounds__(256) void lin_k(const float* __restrict__ X, int xs,
                                             const float* __restrict__ W,
                                             const float* __restrict__ bias,
                                             const float* __restrict__ g, const float* __restrict__ bb,
                                             float* __restrict__ Y, int ys) {
    int wid = (blockIdx.x * 256 + threadIdx.x) >> 6;
    int lane = threadIdx.x & 63;
    int o = wid >> 3;          // NB = 8
    int b = wid & 7;
    const float4* wr = (const float4*)(W + (size_t)o * C);
    const float4* xr = (const float4*)(X + (size_t)b * xs);
    float acc = 0.f;
#pragma unroll
    for (int i = 0; i < C/256; i++) {
        float4 w = wr[lane + 64*i];
        float4 xv = xr[lane + 64*i];
        acc = fmaf(w.x,xv.x, fmaf(w.y,xv.y, fmaf(w.z,xv.z, fmaf(w.w,xv.w, acc))));
    }
#pragma unroll
    for (int off = 32; off > 0; off >>= 1) acc += __shfl_xor(acc, off);
    if (lane == 0) {
        if constexpr (HASBIAS) acc += bias[o];
        if constexpr (ACT) acc = lrelu(fmaf(acc, g[o] * BN_SC, bb[o]));
        Y[(size_t)b * ys + o] = acc;
    }
}

extern "C" void kernel_launch(void* const* d_in, const int* in_sizes, int n_in,
                              void* d_out, int out_size, void* d_ws, size_t ws_size,
                              hipStream_t stream) {
    const float* x       = (const float*)d_in[0];
    const float* conv1_w = (const float*)d_in[1];
    const float* conv1_b = (const float*)d_in[2];
    const float* bn1_g   = (const float*)d_in[3];
    const float* bn1_b   = (const float*)d_in[4];
    const float* conv2_w = (const float*)d_in[5];
    const float* bn2_g   = (const float*)d_in[6];
    const float* bn2_b   = (const float*)d_in[7];
    const float* conv3_w = (const float*)d_in[8];
    const float* bn3_g   = (const float*)d_in[9];
    const float* bn3_b   = (const float*)d_in[10];
    const float* conv4_w = (const float*)d_in[11];
    const float* bn4_g   = (const float*)d_in[12];
    const float* bn4_b   = (const float*)d_in[13];
    const float* conv5_w = (const float*)d_in[14];
    const float* lin1_w  = (const float*)d_in[15];
    const float* bn6_g   = (const float*)d_in[16];
    const float* bn6_b   = (const float*)d_in[17];
    const float* lin2_w  = (const float*)d_in[18];
    const float* lin2_b  = (const float*)d_in[19];
    const float* bn7_g   = (const float*)d_in[20];
    const float* bn7_b   = (const float*)d_in[21];
    const float* lin3_w  = (const float*)d_in[22];
    const float* lin3_b  = (const float*)d_in[23];
    float* outp = (float*)d_out;

    // workspace layout (floats): total 10,657,792 f = 42.6 MB
    float* ws   = (float*)d_ws;
    float* xc   = ws;                          // (BN,512)          4,194,304
    int*   idxb = (int*)(ws + 4194304);        // (BN,20)             163,840
    float* nrm  = ws + 4194304 + 163840;       // (BN)                  8,192
    float* ft   = nrm + 8192;                  // (B,<=128,N)       1,048,576
    float* part = ft + 1048576;                // (B,64,1024)         524,288
    float* w5t  = part + 524288;               // bf16 wh/wl          524,288
    float* Ht   = w5t + 524288;                // (BN,<=256) / xh   2,097,152
    float* Ct   = Ht + 2097152;                // (BN,<=256) / xl   2,097,152
    // head scratch aliases ft (dead after the last knn_k):
    float* gp   = ft;                          // (8,1024)
    float* y1   = ft + 8192;                   // (8,512)
    float* y2   = ft + 8192 + 4096;            // (8,256)
    // split-bf16 aliases (dead regions after stage 4):
    unsigned short* xhp = (unsigned short*)Ht;       // BN*512 shorts
    unsigned short* xlp = (unsigned short*)Ct;
    unsigned short* whp = (unsigned short*)w5t;      // 1024*512 shorts
    unsigned short* wlp = whp + 1024*512;

    prep_k<<<BN/256, 256, 0, stream>>>(x, ft, nrm);

    // Stage 1: C=3 (coords), O=64, with conv bias; R=2 + XCD swizzle
    knn_k<3, 2><<<BN/8, 256, 0, stream>>>(ft, x, 3, nrm, idxb);
    hc_k<3, 64, true, 4><<<BN/4, 64, 0, stream>>>(x, 3, conv1_w, conv1_b, Ht, Ct);
    gmax_k<64, true><<<BN, 64, 0, stream>>>(Ht, Ct, idxb, bn1_g, bn1_b, xc + 0, ft, nrm);

    // Stage 2: C=64 -> O=64; LDS-staged m-stream, R=2 (16 waves/CU)
    knn_k<64, 2><<<BN/8, 256, 0, stream>>>(ft, xc + 0, XC_C, nrm, idxb);
    hc_k<64, 64, false, 4><<<BN/4, 64, 0, stream>>>(xc + 0, XC_C, conv2_w, nullptr, Ht, Ct);
    gmax_k<64, true><<<BN, 64, 0, stream>>>(Ht, Ct, idxb, bn2_g, bn2_b, xc + 64, ft, nrm);

    // Stage 3: C=64 -> O=128
    knn_k<64, 2><<<BN/8, 256, 0, stream>>>(ft, xc + 64, XC_C, nrm, idxb);
    hc_k<64, 128, false, 4><<<BN/4, 128, 0, stream>>>(xc + 64, XC_C, conv3_w, nullptr, Ht, Ct);
    gmax_k<128, true><<<BN, 128, 0, stream>>>(Ht, Ct, idxb, bn3_g, bn3_b, xc + 128, ft, nrm);

    // Stage 4: C=128 -> O=256 (no next knn)
    knn_k<128, 2><<<BN/8, 256, 0, stream>>>(ft, xc + 128, XC_C, nrm, idxb);
    hc_k<128, 256, false, 8><<<BN/8, 256, 0, stream>>>(xc + 128, XC_C, conv4_w, nullptr, Ht, Ct);
    gmax_k<256, false><<<BN, 256, 0, stream>>>(Ht, Ct, idxb, bn4_g, bn4_b, xc + 256, nullptr, nullptr);

    // conv5 (32-row tile) + global max pool + head
    xcvt_k<<<BN*512/256, 256, 0, stream>>>(xc, xhp, xlp);
    wcvt_k<<<1024*512/256, 256, 0, stream>>>(conv5_w, whp, wlp);
    conv5mfma_k<<<dim3(32, 8, NB), 256, 0, stream>>>(xhp, xlp, whp, wlp, part);
    gpool_k<<<NB*1024/256, 256, 0, stream>>>(part, gp);
    lin_k<1024, false, true><<<NB*512/4, 256, 0, stream>>>(gp, 1024, lin1_w, nullptr, bn6_g, bn6_b, y1, 512);
    lin_k<512,  true,  true><<<NB*256/4, 256, 0, stream>>>(y1, 512, lin2_w, lin2_b, bn7_g, bn7_b, y2, 256);
    lin_k<256,  true, false><<<NB*40/4,  256, 0, stream>>>(y2, 256, lin3_w, lin3_b, nullptr, nullptr, outp, 40);
}

// Round 15
// 391.404 us; speedup vs baseline: 1.3345x; 1.0922x over previous
//
#include <hip/hip_runtime.h>
#include <cmath>
#include <cstdint>
#include <cstddef>

#define NB 8
#define NPTS 1024
#define BN (NB*NPTS)
#define KNN 20
#define XC_C 512
#define BN_SC 0.99999500003749973f  // 1/sqrt(1+1e-5)

static __device__ __forceinline__ float lrelu(float z) { return z >= 0.f ? z : 0.01f * z; }

// Interleaved DPP max step for TWO independent (lo,hi) u64 chains — R2/R12-validated on HW.
// (Used only by the rare fallback path.)
template<int CTRL>
static __device__ __forceinline__ void dpp_max2(unsigned& loA, unsigned& hiA,
                                                unsigned& loB, unsigned& hiB) {
    unsigned tlA = (unsigned)__builtin_amdgcn_update_dpp(0, (int)loA, CTRL, 0xF, 0xF, false);
    unsigned thA = (unsigned)__builtin_amdgcn_update_dpp(0, (int)hiA, CTRL, 0xF, 0xF, false);
    unsigned tlB = (unsigned)__builtin_amdgcn_update_dpp(0, (int)loB, CTRL, 0xF, 0xF, false);
    unsigned thB = (unsigned)__builtin_amdgcn_update_dpp(0, (int)hiB, CTRL, 0xF, 0xF, false);
    unsigned long long a = ((unsigned long long)hiA << 32) | loA;
    unsigned long long b = ((unsigned long long)thA << 32) | tlA;
    if (b > a) { loA = tlA; hiA = thA; }
    unsigned long long c = ((unsigned long long)hiB << 32) | loB;
    unsigned long long d = ((unsigned long long)thB << 32) | tlB;
    if (d > c) { loB = tlB; hiB = thB; }
}

static __device__ __forceinline__ void wave_max_u64_x2(unsigned long long vA, unsigned long long vB,
                                                       unsigned long long& winA, unsigned long long& winB) {
    unsigned loA = (unsigned)vA, hiA = (unsigned)(vA >> 32);
    unsigned loB = (unsigned)vB, hiB = (unsigned)(vB >> 32);
    dpp_max2<0x121>(loA, hiA, loB, hiB);
    dpp_max2<0x122>(loA, hiA, loB, hiB);
    dpp_max2<0x124>(loA, hiA, loB, hiB);
    dpp_max2<0x128>(loA, hiA, loB, hiB);
    dpp_max2<0x142>(loA, hiA, loB, hiB);   // row_bcast15
    dpp_max2<0x143>(loA, hiA, loB, hiB);   // row_bcast31; lane63 = wave max
    unsigned wloA = (unsigned)__builtin_amdgcn_readlane((int)loA, 63);
    unsigned whiA = (unsigned)__builtin_amdgcn_readlane((int)hiA, 63);
    unsigned wloB = (unsigned)__builtin_amdgcn_readlane((int)loB, 63);
    unsigned whiB = (unsigned)__builtin_amdgcn_readlane((int)hiB, 63);
    winA = ((unsigned long long)whiA << 32) | wloA;
    winB = ((unsigned long long)whiB << 32) | wloB;
}

// ---- cross-lane helpers for the threshold-prune selection path (R1-validated) ----
static __device__ __forceinline__ unsigned long long shflx64(unsigned long long v, int m) {
    int lo = __shfl_xor((int)(unsigned)v, m);
    int hi = __shfl_xor((int)(unsigned)(v >> 32), m);
    return ((unsigned long long)(unsigned)hi << 32) | (unsigned)lo;
}

static __device__ __forceinline__ unsigned long long rdlane64(unsigned long long v, int l) {
    unsigned lo = (unsigned)__builtin_amdgcn_readlane((int)(unsigned)v, l);
    unsigned hi = (unsigned)__builtin_amdgcn_readlane((int)(unsigned)(v >> 32), l);
    return ((unsigned long long)hi << 32) | lo;
}

// 64-lane bitonic sort, descending, TWO independent u64 chains interleaved for ILP.
static __device__ __forceinline__ void bitonic64_desc_x2(unsigned long long& vA,
                                                         unsigned long long& vB, int lane) {
#pragma unroll
    for (int k = 2; k <= 64; k <<= 1) {
#pragma unroll
        for (int j = k >> 1; j > 0; j >>= 1) {
            unsigned long long pA = shflx64(vA, j);
            unsigned long long pB = shflx64(vB, j);
            bool takeMax = (((lane & k) == 0) == ((lane & j) == 0));
            vA = ((pA > vA) == takeMax) ? pA : vA;
            vB = ((pB > vB) == takeMax) ? pB : vB;
        }
    }
}

// ---- R1/R5-validated selection for a pair of rows, from their distance accumulators. ----
static __device__ __forceinline__ void select_pair(const float4* accA, const float4* accB,
                                                   const float4* nm4, int lane,
                                                   unsigned long long (*cw)[64],
                                                   int rA, int rB, int* __restrict__ idx) {
    unsigned long long keyA[16], keyB[16];
#pragma unroll
    for (int j = 0; j < 4; j++) {
        float4 nm = nm4[lane + 64*j];
#pragma unroll
        for (int q = 0; q < 4; q++) {
            int m = 4*(lane + 64*j) + q;
            float fA = 2.f * (&accA[j].x)[q] - (&nm.x)[q];
            unsigned uA = __float_as_uint(fA);
            unsigned sA_ = (unsigned)((int)uA >> 31);
            uA ^= (sA_ | 0x80000000u);
            keyA[4*j+q] = ((unsigned long long)uA << 32) | (unsigned)(1023 - m);
            float fB = 2.f * (&accB[j].x)[q] - (&nm.x)[q];
            unsigned uB = __float_as_uint(fB);
            unsigned sB_ = (unsigned)((int)uB >> 31);
            uB ^= (sB_ | 0x80000000u);
            keyB[4*j+q] = ((unsigned long long)uB << 32) | (unsigned)(1023 - m);
        }
    }

    // per-lane heads
    unsigned long long hA = keyA[0], hB = keyB[0];
#pragma unroll
    for (int i = 1; i < 16; i++) {
        hA = keyA[i] > hA ? keyA[i] : hA;
        hB = keyB[i] > hB ? keyB[i] : hB;
    }

    // L = 20th largest head
    unsigned long long shA = hA, shB = hB;
    bitonic64_desc_x2(shA, shB, lane);
    unsigned long long LA = rdlane64(shA, KNN - 1);
    unsigned long long LB = rdlane64(shB, KNN - 1);

    // count + wave prefix scan
    int cA = 0, cB = 0;
#pragma unroll
    for (int i = 0; i < 16; i++) {
        cA += (keyA[i] >= LA) ? 1 : 0;
        cB += (keyB[i] >= LB) ? 1 : 0;
    }
    int sA = cA, sB = cB;
#pragma unroll
    for (int off = 1; off < 64; off <<= 1) {
        int tA = __shfl_up(sA, off);
        int tB = __shfl_up(sB, off);
        if (lane >= off) { sA += tA; sB += tB; }
    }
    int totA = __builtin_amdgcn_readlane(sA, 63);     // wave-uniform
    int totB = __builtin_amdgcn_readlane(sB, 63);
    int pA = sA - cA, pB = sB - cB;                   // exclusive prefix

    if (totA <= 64 && totB <= 64) {
        int wa = pA, wb = pB;
#pragma unroll
        for (int i = 0; i < 16; i++) {
            if (keyA[i] >= LA) cw[0][wa++] = keyA[i];
            if (keyB[i] >= LB) cw[1][wb++] = keyB[i];
        }
        // same-wave LDS RAW: drain lgkm before reads, block compile-time motion.
        asm volatile("s_waitcnt lgkmcnt(0)" ::: "memory");
        unsigned long long vA = 0ull, vB = 0ull;
        if (lane < totA) vA = cw[0][lane];
        if (lane < totB) vB = cw[1][lane];
        bitonic64_desc_x2(vA, vB, lane);              // sentinels to back; tot >= 20 always
        if (lane < KNN) {
            idx[rA * KNN + lane] = 1023 - (int)(unsigned)vA;
            idx[rB * KNN + lane] = 1023 - (int)(unsigned)vB;
        }
    } else {
        // fallback: per-lane bitonic sort + 20-round DPP pop (wave-uniform branch).
#pragma unroll
        for (int ksz = 2; ksz <= 16; ksz <<= 1) {
#pragma unroll
            for (int jst = ksz >> 1; jst > 0; jst >>= 1) {
#pragma unroll
                for (int i = 0; i < 16; i++) {
                    int l = i ^ jst;
                    if (l > i) {
                        bool dsc = (i & ksz) == 0;
                        unsigned long long a = keyA[i], bbv = keyA[l];
                        bool swA = dsc ? (a < bbv) : (a > bbv);
                        if (swA) { keyA[i] = bbv; keyA[l] = a; }
                        unsigned long long c = keyB[i], d = keyB[l];
                        bool swB = dsc ? (c < d) : (c > d);
                        if (swB) { keyB[i] = d; keyB[l] = c; }
                    }
                }
            }
        }
        int mineA = 0, mineB = 0;
        for (int kk = 0; kk < KNN; kk++) {       // not unrolled
            unsigned long long winA, winB;
            wave_max_u64_x2(keyA[0], keyB[0], winA, winB);
            if (lane == kk) {
                mineA = 1023 - (int)(unsigned)winA;
                mineB = 1023 - (int)(unsigned)winB;
            }
            bool popA = (keyA[0] == winA);
            bool popB = (keyB[0] == winB);
#pragma unroll
            for (int t = 0; t < 15; t++) {
                keyA[t] = popA ? keyA[t+1] : keyA[t];
                keyB[t] = popB ? keyB[t+1] : keyB[t];
            }
            keyA[15] = popA ? 0ull : keyA[15];
            keyB[15] = popB ? 0ull : keyB[15];
        }
        if (lane < KNN) {
            idx[rA * KNN + lane] = mineA;
            idx[rB * KNN + lane] = mineB;
        }
    }
}

// ---- knn distance+select body (R10/R13-validated), callable from fused kernel ----
template<int C, int R>
static __device__ __forceinline__ void knn_body(int blk,
                                                const float* __restrict__ ft,
                                                const float* __restrict__ frow, int frs,
                                                const float* __restrict__ nrm,
                                                int* __restrict__ idx,
                                                unsigned long long (*cand)[2][64],
                                                float* sbuf) {
    int tid = threadIdx.x;
    int w = tid >> 6;
    int lane = tid & 63;
    int b    = blk & 7;                     // batch == XCD (round-robin dispatch heuristic)
    int slot = blk >> 3;                    // row-block within batch
    int r0 = b * NPTS + slot * (4*R) + R * w;   // R consecutive rows per wave
    const float* ftb = ft + (size_t)b * C * NPTS;

    float4 acc[R][4];
#pragma unroll
    for (int rr = 0; rr < R; rr++)
#pragma unroll
        for (int j = 0; j < 4; j++) acc[rr][j] = make_float4(0.f,0.f,0.f,0.f);

    if constexpr ((C & 3) == 0) {
        constexpr int NC = C / 4;
        const float4* cr0 = (const float4*)(frow + (size_t)r0 * frs);
        int frs4 = frs >> 2;
        const float4* src4 = (const float4*)ftb;     // channel c = 256 float4 row
        float4 pf[4];
        // prologue: stage chunk 0 (channels 0..3) -> buf0
#pragma unroll
        for (int i = 0; i < 4; i++) pf[i] = src4[i*256 + tid];
        {
            float4* sw = (float4*)sbuf;
#pragma unroll
            for (int i = 0; i < 4; i++) sw[i*256 + tid] = pf[i];
        }
        __syncthreads();
        for (int c4 = 0; c4 < NC; c4++) {
            int cur = c4 & 1;
            if (c4 + 1 < NC) {               // issue next chunk's global loads early
#pragma unroll
                for (int i = 0; i < 4; i++) pf[i] = src4[(size_t)(4*(c4+1)+i)*256 + tid];
            }
            float4 ct[R];
#pragma unroll
            for (int rr = 0; rr < R; rr++) ct[rr] = cr0[c4 + rr*frs4];
            const float4* sc = (const float4*)(sbuf + cur * 4 * NPTS);
#pragma unroll
            for (int cc = 0; cc < 4; cc++) {
                const float4* rm = sc + cc*256;
#pragma unroll
                for (int j = 0; j < 4; j++) {
                    float4 v = rm[lane + 64*j];          // LDS, lane-consecutive: conflict-free
#pragma unroll
                    for (int rr = 0; rr < R; rr++) {
                        float cs = (&ct[rr].x)[cc];
                        acc[rr][j].x = fmaf(cs, v.x, acc[rr][j].x);
                        acc[rr][j].y = fmaf(cs, v.y, acc[rr][j].y);
                        acc[rr][j].z = fmaf(cs, v.z, acc[rr][j].z);
                        acc[rr][j].w = fmaf(cs, v.w, acc[rr][j].w);
                    }
                }
            }
            if (c4 + 1 < NC) {
                float4* sw = (float4*)(sbuf + (cur ^ 1) * 4 * NPTS);
#pragma unroll
                for (int i = 0; i < 4; i++) sw[i*256 + tid] = pf[i];
                __syncthreads();             // writes visible before next chunk's reads
            }
        }
    } else {
        for (int c = 0; c < C; c++) {
            float ct[R];
#pragma unroll
            for (int rr = 0; rr < R; rr++) ct[rr] = frow[(size_t)(r0+rr) * frs + c];
            const float4* rm = (const float4*)(ftb + (size_t)c * NPTS);
#pragma unroll
            for (int j = 0; j < 4; j++) {
                float4 v = rm[lane + 64*j];
#pragma unroll
                for (int rr = 0; rr < R; rr++) {
                    float cs = ct[rr];
                    acc[rr][j].x = fmaf(cs, v.x, acc[rr][j].x);
                    acc[rr][j].y = fmaf(cs, v.y, acc[rr][j].y);
                    acc[rr][j].z = fmaf(cs, v.z, acc[rr][j].z);
                    acc[rr][j].w = fmaf(cs, v.w, acc[rr][j].w);
                }
            }
        }
    }

    const float4* nm4 = (const float4*)(nrm + b * NPTS);
#pragma unroll
    for (int p = 0; p < R/2; p++)
        select_pair(acc[2*p], acc[2*p+1], nm4, lane, cand[w], r0 + 2*p, r0 + 2*p + 1, idx);
}

// ---- standalone knn (stages 1-3) ----
template<int C, int R>
__global__ __launch_bounds__(256, 2) void knn_k(const float* __restrict__ ft,
                                                const float* __restrict__ frow, int frs,
                                                const float* __restrict__ nrm,
                                                int* __restrict__ idx) {
    __shared__ unsigned long long cand[4][2][64];
    __shared__ float sbuf[((C & 3) == 0) ? 2 * 4 * NPTS : 1];
    knn_body<C, R>(blockIdx.x, ft, frow, frs, nrm, idx, cand, &sbuf[0]);
}

// ---- hc body (bit-identical chains), callable from fused kernel ----
template<int C, int O, bool HASB, int RPB>
static __device__ __forceinline__ void hc_body(int blk,
                                               const float* __restrict__ F, int FS,
                                               const float* __restrict__ w, const float* __restrict__ bias,
                                               float* __restrict__ Ht, float* __restrict__ Ct) {
    int r0 = blk * RPB;
    int o = threadIdx.x;
    const float* wr = w + (size_t)o * (2*C);
    float h[RPB], a2[RPB];
#pragma unroll
    for (int nn = 0; nn < RPB; nn++) { h[nn] = 0.f; a2[nn] = 0.f; }
    if constexpr ((C & 3) == 0) {
        const float4* w1 = (const float4*)wr;
        const float4* w2 = (const float4*)(wr + C);
#pragma unroll 4
        for (int c4 = 0; c4 < C/4; c4++) {
            float4 wa = w1[c4], wb = w2[c4];
#pragma unroll
            for (int nn = 0; nn < RPB; nn++) {
                float4 f = *(const float4*)(F + (size_t)(r0+nn)*FS + 4*c4);  // broadcast
                h[nn]  = fmaf(wa.x,f.x, fmaf(wa.y,f.y, fmaf(wa.z,f.z, fmaf(wa.w,f.w, h[nn]))));
                a2[nn] = fmaf(wb.x,f.x, fmaf(wb.y,f.y, fmaf(wb.z,f.z, fmaf(wb.w,f.w, a2[nn]))));
            }
        }
    } else {
        for (int c = 0; c < C; c++) {
            float wa = wr[c], wb = wr[C+c];
#pragma unroll
            for (int nn = 0; nn < RPB; nn++) {
                float f = F[(size_t)(r0+nn)*FS + c];
                h[nn]  = fmaf(wa, f, h[nn]);
                a2[nn] = fmaf(wb, f, a2[nn]);
            }
        }
    }
    float bs = 0.f;
    if constexpr (HASB) bs = bias[o];
#pragma unroll
    for (int nn = 0; nn < RPB; nn++) {
        size_t ro = (size_t)(r0+nn)*O + o;
        Ht[ro] = h[nn];
        Ct[ro] = a2[nn] - h[nn] + bs;
    }
}

// ---- standalone hc (stages 1-3) ----
template<int C, int O, bool HASB, int RPB>
__global__ void hc_k(const float* __restrict__ F, int FS,
                     const float* __restrict__ w, const float* __restrict__ bias,
                     float* __restrict__ Ht, float* __restrict__ Ct) {
    hc_body<C, O, HASB, RPB>(blockIdx.x, F, FS, w, bias, Ht, Ct);
}

// ---- FUSED stage-4 kernel: blocks [0,knnBlocks) run knn<C,R>; rest run hc<C,O,RPB>.
// R14 POST-MORTEM rationale: knn runs at 34% VALU / 1% HBM / 20% occupancy — the CU
// is mostly idle; hc (independent: reads F=xc, not idx) previously ran serially after.
// Mixing block types lets hc's memory/FMA work fill knn's stall cycles. Each block
// executes EXACTLY its standalone code path -> bit-identical outputs, absmax 0.0.
template<int C, int R, int O, int RPB>
__global__ __launch_bounds__(256, 2) void knnhc_k(const float* __restrict__ ft,
                                                  const float* __restrict__ frow, int frs,
                                                  const float* __restrict__ nrm,
                                                  int* __restrict__ idx,
                                                  const float* __restrict__ w4,
                                                  float* __restrict__ Ht, float* __restrict__ Ct,
                                                  int knnBlocks) {
    __shared__ unsigned long long cand[4][2][64];
    __shared__ float sbuf[2 * 4 * NPTS];
    if ((int)blockIdx.x < knnBlocks) {
        knn_body<C, R>(blockIdx.x, ft, frow, frs, nrm, idx, cand, &sbuf[0]);
    } else {
        hc_body<C, O, false, RPB>(blockIdx.x - knnBlocks, frow, frs, w4, nullptr, Ht, Ct);
    }
}

// ---- bf16 split helpers (RNE) ----
static __device__ __forceinline__ unsigned short f2bf(float f) {
    unsigned u = __float_as_uint(f);
    unsigned r = u + 0x7fffu + ((u >> 16) & 1u);
    return (unsigned short)(r >> 16);
}
static __device__ __forceinline__ float bf2f(unsigned short h) {
    return __uint_as_float(((unsigned)h) << 16);
}

typedef __attribute__((ext_vector_type(8))) short short8;
typedef __attribute__((ext_vector_type(4))) float floatx4;

// ---- prep: x (B,N,3) -> ft (B,3,N) + norms ----
__global__ void prep_k(const float* __restrict__ x, float* __restrict__ ft, float* __restrict__ nrm) {
    int i = blockIdx.x * 256 + threadIdx.x;   // b*N+n
    if (i >= BN) return;
    int b = i >> 10, n = i & 1023;
    float a = x[3*i], c = x[3*i+1], d = x[3*i+2];
    float* fb = ft + (size_t)b * 3 * NPTS;
    fb[n] = a; fb[NPTS + n] = c; fb[2*NPTS + n] = d;
    nrm[i] = a*a + c*c + d*d;
}

// ---- gather + max_k + bn + lrelu; optional transposed-feature + norms for next knn ----
// XCD-swizzled r mapping (R8-validated): batch = blockIdx&7 keeps gathers in-XCD.
template<int O, bool WFT>
__global__ void gmax_k(const float* __restrict__ Ht, const float* __restrict__ Ct,
                       const int* __restrict__ idx,
                       const float* __restrict__ g, const float* __restrict__ bb,
                       float* __restrict__ xcs, float* __restrict__ ft, float* __restrict__ nrm) {
    int b = blockIdx.x & 7;
    int n = blockIdx.x >> 3;
    int r = b * NPTS + n;
    int o = threadIdx.x;
    const int* id = idx + r * KNN;
    float vmax = -INFINITY, vmin = INFINITY;
    const float* hb = Ht + (size_t)b * NPTS * O + o;
#pragma unroll 4
    for (int k = 0; k < KNN; k++) {
        int m = id[k];                 // broadcast
        float v = hb[(size_t)m * O];   // coalesced across o
        vmax = fmaxf(vmax, v); vmin = fminf(vmin, v);
    }
    float ct = Ct[(size_t)r * O + o];
    float s = g[o] * BN_SC;
    float pre = (s >= 0.f ? vmax : vmin) + ct;
    float out = lrelu(fmaf(s, pre, bb[o]));
    xcs[(size_t)r * XC_C + o] = out;
    if constexpr (WFT) {
        ft[((size_t)b * O + o) * NPTS + n] = out;
        float sq = out * out;
#pragma unroll
        for (int off = 32; off > 0; off >>= 1) sq += __shfl_xor(sq, off);
        __shared__ float red[O/64 > 0 ? O/64 : 1];
        if ((o & 63) == 0) red[o >> 6] = sq;
        __syncthreads();
        if (o == 0) {
            float t = 0.f;
#pragma unroll
            for (int i = 0; i < O/64; i++) t += red[i];
            nrm[r] = t;
        }
    }
}

// ---- split-bf16 conversions for conv5 MFMA ----
__global__ void xcvt_k(const float* __restrict__ xc,
                       unsigned short* __restrict__ xh, unsigned short* __restrict__ xl) {
    int i = blockIdx.x * 256 + threadIdx.x;   // BN*512
    float v = xc[i];
    unsigned short h = f2bf(v);
    xh[i] = h;
    xl[i] = f2bf(v - bf2f(h));
}

__global__ void wcvt_k(const float* __restrict__ w5,
                       unsigned short* __restrict__ wh, unsigned short* __restrict__ wl) {
    int i = blockIdx.x * 256 + threadIdx.x;   // 1024*512, (o,c) row-major kept
    float v = w5[i];
    unsigned short h = f2bf(v);
    wh[i] = h;
    wl[i] = f2bf(v - bf2f(h));
}

// ---- conv5 via LDS-staged split-bf16 MFMA (32-row tile, R10-proven 48us) + T14 hoist ----
__global__ __launch_bounds__(256) void conv5mfma_k(const unsigned short* __restrict__ xh,
                                                   const unsigned short* __restrict__ xl,
                                                   const unsigned short* __restrict__ wh,
                                                   const unsigned short* __restrict__ wl,
                                                   float* __restrict__ part) {
    __shared__ short ah_s[32*72];
    __shared__ short al_s[32*72];
    __shared__ short bh_s[128*72];
    __shared__ short bl_s[128*72];
    int b = blockIdx.z, og = blockIdx.y, nt = blockIdx.x;   // nt 0..31
    int tid = threadIdx.x;
    int w = tid >> 6, lane = tid & 63;
    int m = lane & 15, quad = lane >> 4;
    int h = w >> 1, q = w & 1;
    size_t nbase = (size_t)b * NPTS + nt * 32;
    int obase = og * 128;
    int srow = tid >> 3;
    int scol = (tid & 7) * 8;

    floatx4 acc[4];
#pragma unroll
    for (int t = 0; t < 4; t++) acc[t] = (floatx4){0.f, 0.f, 0.f, 0.f};

    for (int kc = 0; kc < 512; kc += 64) {
        short8 pa[2], pb[8];
        pa[0] = *(const short8*)(xh + (nbase + srow)*512 + kc + scol);
        pa[1] = *(const short8*)(xl + (nbase + srow)*512 + kc + scol);
#pragma unroll
        for (int i = 0; i < 4; i++) {
            int r = srow + i*32;
            pb[2*i]   = *(const short8*)(wh + (size_t)(obase + r)*512 + kc + scol);
            pb[2*i+1] = *(const short8*)(wl + (size_t)(obase + r)*512 + kc + scol);
        }
        __syncthreads();
        *(short8*)(ah_s + srow*72 + scol) = pa[0];
        *(short8*)(al_s + srow*72 + scol) = pa[1];
#pragma unroll
        for (int i = 0; i < 4; i++) {
            int r = srow + i*32;
            *(short8*)(bh_s + r*72 + scol) = pb[2*i];
            *(short8*)(bl_s + r*72 + scol) = pb[2*i+1];
        }
        __syncthreads();
#pragma unroll
        for (int kk = 0; kk < 2; kk++) {
            short8 ah8 = *(const short8*)(ah_s + (h*16 + m)*72 + kk*32 + quad*8);
            short8 al8 = *(const short8*)(al_s + (h*16 + m)*72 + kk*32 + quad*8);
#pragma unroll
            for (int t = 0; t < 4; t++) {
                short8 bh8 = *(const short8*)(bh_s + (q*64 + t*16 + m)*72 + kk*32 + quad*8);
                short8 bl8 = *(const short8*)(bl_s + (q*64 + t*16 + m)*72 + kk*32 + quad*8);
                acc[t] = __builtin_amdgcn_mfma_f32_16x16x32_bf16(ah8, bh8, acc[t], 0, 0, 0);
                acc[t] = __builtin_amdgcn_mfma_f32_16x16x32_bf16(ah8, bl8, acc[t], 0, 0, 0);
                acc[t] = __builtin_amdgcn_mfma_f32_16x16x32_bf16(al8, bh8, acc[t], 0, 0, 0);
            }
        }
    }
#pragma unroll
    for (int t = 0; t < 4; t++) {
        float v = fmaxf(fmaxf(acc[t][0], acc[t][1]), fmaxf(acc[t][2], acc[t][3]));
        v = fmaxf(v, __shfl_xor(v, 16));
        v = fmaxf(v, __shfl_xor(v, 32));
        if (quad == 0)
            part[((size_t)b * 64 + nt*2 + h) * 1024 + obase + q*64 + t*16 + m] = v;
    }
}

// ---- global max pool: gp[b,o] = max_j part[b,j,o] ----
__global__ void gpool_k(const float* __restrict__ part, float* __restrict__ gp) {
    int i = blockIdx.x * 256 + threadIdx.x;   // b*1024+o
    int b = i >> 10, o = i & 1023;
    const float* pb = part + (size_t)b * 64 * 1024 + o;
    float m = pb[0];
#pragma unroll 4
    for (int j = 1; j < 64; j++) m = fmaxf(m, pb[(size_t)j * 1024]);
    gp[i] = m;
}

// ---- linear layer, one wave per output dot ----
template<int C, bool HASBIAS, bool ACT>
__global__ __launch_bounds__(256) void lin_k(const float* __restrict__ X, int xs,
                                             const float* __restrict__ W,
                                             const float* __restrict__ bias,
                                             const float* __restrict__ g, const float* __restrict__ bb,
                                             float* __restrict__ Y, int ys) {
    int wid = (blockIdx.x * 256 + threadIdx.x) >> 6;
    int lane = threadIdx.x & 63;
    int o = wid >> 3;          // NB = 8
    int b = wid & 7;
    const float4* wr = (const float4*)(W + (size_t)o * C);
    const float4* xr = (const float4*)(X + (size_t)b * xs);
    float acc = 0.f;
#pragma unroll
    for (int i = 0; i < C/256; i++) {
        float4 w = wr[lane + 64*i];
        float4 xv = xr[lane + 64*i];
        acc = fmaf(w.x,xv.x, fmaf(w.y,xv.y, fmaf(w.z,xv.z, fmaf(w.w,xv.w, acc))));
    }
#pragma unroll
    for (int off = 32; off > 0; off >>= 1) acc += __shfl_xor(acc, off);
    if (lane == 0) {
        if constexpr (HASBIAS) acc += bias[o];
        if constexpr (ACT) acc = lrelu(fmaf(acc, g[o] * BN_SC, bb[o]));
        Y[(size_t)b * ys + o] = acc;
    }
}

extern "C" void kernel_launch(void* const* d_in, const int* in_sizes, int n_in,
                              void* d_out, int out_size, void* d_ws, size_t ws_size,
                              hipStream_t stream) {
    const float* x       = (const float*)d_in[0];
    const float* conv1_w = (const float*)d_in[1];
    const float* conv1_b = (const float*)d_in[2];
    const float* bn1_g   = (const float*)d_in[3];
    const float* bn1_b   = (const float*)d_in[4];
    const float* conv2_w = (const float*)d_in[5];
    const float* bn2_g   = (const float*)d_in[6];
    const float* bn2_b   = (const float*)d_in[7];
    const float* conv3_w = (const float*)d_in[8];
    const float* bn3_g   = (const float*)d_in[9];
    const float* bn3_b   = (const float*)d_in[10];
    const float* conv4_w = (const float*)d_in[11];
    const float* bn4_g   = (const float*)d_in[12];
    const float* bn4_b   = (const float*)d_in[13];
    const float* conv5_w = (const float*)d_in[14];
    const float* lin1_w  = (const float*)d_in[15];
    const float* bn6_g   = (const float*)d_in[16];
    const float* bn6_b   = (const float*)d_in[17];
    const float* lin2_w  = (const float*)d_in[18];
    const float* lin2_b  = (const float*)d_in[19];
    const float* bn7_g   = (const float*)d_in[20];
    const float* bn7_b   = (const float*)d_in[21];
    const float* lin3_w  = (const float*)d_in[22];
    const float* lin3_b  = (const float*)d_in[23];
    float* outp = (float*)d_out;

    // workspace layout (floats): total 10,657,792 f = 42.6 MB
    float* ws   = (float*)d_ws;
    float* xc   = ws;                          // (BN,512)          4,194,304
    int*   idxb = (int*)(ws + 4194304);        // (BN,20)             163,840
    float* nrm  = ws + 4194304 + 163840;       // (BN)                  8,192
    float* ft   = nrm + 8192;                  // (B,<=128,N)       1,048,576
    float* part = ft + 1048576;                // (B,64,1024)         524,288
    float* w5t  = part + 524288;               // bf16 wh/wl          524,288
    float* Ht   = w5t + 524288;                // (BN,<=256) / xh   2,097,152
    float* Ct   = Ht + 2097152;                // (BN,<=256) / xl   2,097,152
    // head scratch aliases ft (dead after the last knn_k):
    float* gp   = ft;                          // (8,1024)
    float* y1   = ft + 8192;                   // (8,512)
    float* y2   = ft + 8192 + 4096;            // (8,256)
    // split-bf16 aliases (dead regions after stage 4):
    unsigned short* xhp = (unsigned short*)Ht;       // BN*512 shorts
    unsigned short* xlp = (unsigned short*)Ct;
    unsigned short* whp = (unsigned short*)w5t;      // 1024*512 shorts
    unsigned short* wlp = whp + 1024*512;

    prep_k<<<BN/256, 256, 0, stream>>>(x, ft, nrm);

    // Stage 1: C=3 (coords), O=64, with conv bias; R=4 + XCD swizzle
    knn_k<3, 4><<<BN/16, 256, 0, stream>>>(ft, x, 3, nrm, idxb);
    hc_k<3, 64, true, 4><<<BN/4, 64, 0, stream>>>(x, 3, conv1_w, conv1_b, Ht, Ct);
    gmax_k<64, true><<<BN, 64, 0, stream>>>(Ht, Ct, idxb, bn1_g, bn1_b, xc + 0, ft, nrm);

    // Stage 2: C=64 -> O=64; LDS-staged m-stream, R=4
    knn_k<64, 4><<<BN/16, 256, 0, stream>>>(ft, xc + 0, XC_C, nrm, idxb);
    hc_k<64, 64, false, 4><<<BN/4, 64, 0, stream>>>(xc + 0, XC_C, conv2_w, nullptr, Ht, Ct);
    gmax_k<64, true><<<BN, 64, 0, stream>>>(Ht, Ct, idxb, bn2_g, bn2_b, xc + 64, ft, nrm);

    // Stage 3: C=64 -> O=128
    knn_k<64, 4><<<BN/16, 256, 0, stream>>>(ft, xc + 64, XC_C, nrm, idxb);
    hc_k<64, 128, false, 4><<<BN/4, 128, 0, stream>>>(xc + 64, XC_C, conv3_w, nullptr, Ht, Ct);
    gmax_k<128, true><<<BN, 128, 0, stream>>>(Ht, Ct, idxb, bn3_g, bn3_b, xc + 128, ft, nrm);

    // Stage 4 FUSED: knn<128,4> (512 blocks) + hc<128,256,8> (1024 blocks) in one
    // dispatch — hc's memory work fills knn's stall cycles. Outputs bit-identical.
    knnhc_k<128, 4, 256, 8><<<BN/16 + BN/8, 256, 0, stream>>>(ft, xc + 128, XC_C, nrm, idxb,
                                                              conv4_w, Ht, Ct, BN/16);
    gmax_k<256, false><<<BN, 256, 0, stream>>>(Ht, Ct, idxb, bn4_g, bn4_b, xc + 256, nullptr, nullptr);

    // conv5 (32-row tile) + global max pool + head
    xcvt_k<<<BN*512/256, 256, 0, stream>>>(xc, xhp, xlp);
    wcvt_k<<<1024*512/256, 256, 0, stream>>>(conv5_w, whp, wlp);
    conv5mfma_k<<<dim3(32, 8, NB), 256, 0, stream>>>(xhp, xlp, whp, wlp, part);
    gpool_k<<<NB*1024/256, 256, 0, stream>>>(part, gp);
    lin_k<1024, false, true><<<NB*512/4, 256, 0, stream>>>(gp, 1024, lin1_w, nullptr, bn6_g, bn6_b, y1, 512);
    lin_k<512,  true,  true><<<NB*256/4, 256, 0, stream>>>(y1, 512, lin2_w, lin2_b, bn7_g, bn7_b, y2, 256);
    lin_k<256,  true, false><<<NB*40/4,  256, 0, stream>>>(y2, 256, lin3_w, lin3_b, nullptr, nullptr, outp, 40);
}